// Round 1
// baseline (5278.011 us; speedup 1.0000x reference)
//
#include <hip/hip_runtime.h>

typedef unsigned short u16;

#define NB 16
#define NC 256
#define NL 2048
#define NG 32
#define CPG 8
#define GN_N (CPG * NL)   // 16384 elements per (batch, group)
#define EPS 1e-5f
#define SCALE 0.0625f     // 1/sqrt(256)

__device__ __forceinline__ float bf2f(u16 a) {
  union { unsigned u; float f; } v; v.u = (unsigned)a << 16; return v.f;
}
__device__ __forceinline__ u16 f2bf(float f) {
  union { float f; unsigned u; } v; v.f = f;
  return (u16)((v.u + 0x7fffu + ((v.u >> 16) & 1u)) >> 16);
}

// ---------------- GroupNorm + ReLU (in-place safe) ----------------
__global__ __launch_bounds__(256)
void gn_relu(const float* __restrict__ x, const float* __restrict__ gw,
             const float* __restrict__ gb, float* __restrict__ out)
{
  const int b = blockIdx.x / NG, g = blockIdx.x % NG;
  const float4* xp = (const float4*)(x + ((size_t)b * NC + g * CPG) * NL);
  float4* op = (float4*)(out + ((size_t)b * NC + g * CPG) * NL);
  float s = 0.f, ss = 0.f;
  for (int i = threadIdx.x; i < GN_N / 4; i += 256) {
    float4 v = xp[i];
    s += (v.x + v.y) + (v.z + v.w);
    ss += (v.x * v.x + v.y * v.y) + (v.z * v.z + v.w * v.w);
  }
#pragma unroll
  for (int o = 32; o > 0; o >>= 1) { s += __shfl_down(s, o); ss += __shfl_down(ss, o); }
  __shared__ float rs[4], rss[4], stat[2];
  if ((threadIdx.x & 63) == 0) { rs[threadIdx.x >> 6] = s; rss[threadIdx.x >> 6] = ss; }
  __syncthreads();
  if (threadIdx.x == 0) {
    float S = rs[0] + rs[1] + rs[2] + rs[3];
    float SS = rss[0] + rss[1] + rss[2] + rss[3];
    float mean = S * (1.f / GN_N);
    float var = SS * (1.f / GN_N) - mean * mean;
    stat[0] = mean; stat[1] = rsqrtf(var + EPS);
  }
  __syncthreads();
  const float mean = stat[0], inv = stat[1];
  for (int i = threadIdx.x; i < GN_N / 4; i += 256) {
    const int c = g * CPG + (i >> 9);   // (i*4)/2048
    const float ga = gw[c] * inv;
    const float be = gb[c] - mean * ga;
    float4 v = xp[i];
    float4 o;
    o.x = fmaxf(fmaf(v.x, ga, be), 0.f);
    o.y = fmaxf(fmaf(v.y, ga, be), 0.f);
    o.z = fmaxf(fmaf(v.z, ga, be), 0.f);
    o.w = fmaxf(fmaf(v.w, ga, be), 0.f);
    op[i] = o;
  }
}

// ---------------- conv1d k=3 pad=1 (cross-correlation, as lax.conv) ----------
// out[b][oc][l] = bias[oc] (+ t[b][oc]) (+ res[b][oc][l]) + sum_ic,d w[oc][ic][d]*x[b][ic][l+d-1]
#define C3_L 256
#define C3_IC 32

__global__ __launch_bounds__(256)
void conv3(const float* __restrict__ x, const float* __restrict__ w,
           const float* __restrict__ bias, const float* __restrict__ tadd,
           const float* __restrict__ res, float* __restrict__ out)
{
  __shared__ float xs[C3_IC][260];        // cols 0..257 used (halo +2), stride 260 keeps 16B align
  __shared__ float ws[C3_IC][3][32];      // [ic][d][oc]
  const int lb = blockIdx.x * C3_L;
  const int ocb = blockIdx.y * 32;
  const int b = blockIdx.z;
  const int tid = threadIdx.x;
  const int lg = tid & 31, og = tid >> 5;
  const int l0 = lg * 4, oc0 = og * 4;

  float acc[4][8];
#pragma unroll
  for (int i = 0; i < 4; ++i)
#pragma unroll
    for (int j = 0; j < 8; ++j) acc[i][j] = 0.f;

  for (int icc = 0; icc < NC; icc += C3_IC) {
    for (int e = tid; e < C3_IC * 258; e += 256) {
      const int i = e / 258, j = e % 258;
      const int gl = lb - 1 + j;
      float v = 0.f;
      if ((unsigned)gl < (unsigned)NL)
        v = x[((size_t)b * NC + icc + i) * NL + gl];
      xs[i][j] = v;
    }
    // e enumerates (ic,d,oc) with oc fastest -> conflict-free LDS store; global read scattered (L2-resident)
    for (int e = tid; e < C3_IC * 3 * 32; e += 256) {
      const int ic = e / 96, d = (e / 32) % 3, oc = e & 31;
      ws[ic][d][oc] = w[((size_t)(ocb + oc) * NC + icc + ic) * 3 + d];
    }
    __syncthreads();
#pragma unroll 2
    for (int ic = 0; ic < C3_IC; ++ic) {
      float xr[12];
      *(float4*)&xr[0] = *(const float4*)&xs[ic][l0];
      *(float2*)&xr[4] = *(const float2*)&xs[ic][l0 + 4];
      *(float4*)&xr[6] = *(const float4*)&xs[ic][128 + l0];
      *(float2*)&xr[10] = *(const float2*)&xs[ic][128 + l0 + 4];
      const float4 wd0 = *(const float4*)&ws[ic][0][oc0];
      const float4 wd1 = *(const float4*)&ws[ic][1][oc0];
      const float4 wd2 = *(const float4*)&ws[ic][2][oc0];
      const float* w0p = (const float*)&wd0;
      const float* w1p = (const float*)&wd1;
      const float* w2p = (const float*)&wd2;
#pragma unroll
      for (int oo = 0; oo < 4; ++oo) {
        const float w0 = w0p[oo], w1 = w1p[oo], w2 = w2p[oo];
#pragma unroll
        for (int li = 0; li < 4; ++li) {
          acc[oo][li]     = fmaf(w2, xr[li + 2], fmaf(w1, xr[li + 1], fmaf(w0, xr[li],     acc[oo][li])));
          acc[oo][li + 4] = fmaf(w2, xr[li + 8], fmaf(w1, xr[li + 7], fmaf(w0, xr[li + 6], acc[oo][li + 4])));
        }
      }
    }
    __syncthreads();
  }
#pragma unroll
  for (int oo = 0; oo < 4; ++oo) {
    const int oc = ocb + oc0 + oo;
    float bv = bias[oc];
    if (tadd) bv += tadd[b * NC + oc];
    const size_t base = ((size_t)b * NC + oc) * NL + lb;
    float4 o0, o1;
    o0.x = acc[oo][0] + bv; o0.y = acc[oo][1] + bv; o0.z = acc[oo][2] + bv; o0.w = acc[oo][3] + bv;
    o1.x = acc[oo][4] + bv; o1.y = acc[oo][5] + bv; o1.z = acc[oo][6] + bv; o1.w = acc[oo][7] + bv;
    if (res) {
      float4 r0 = *(const float4*)(res + base + l0);
      float4 r1 = *(const float4*)(res + base + 128 + l0);
      o0.x += r0.x; o0.y += r0.y; o0.z += r0.z; o0.w += r0.w;
      o1.x += r1.x; o1.y += r1.y; o1.z += r1.z; o1.w += r1.w;
    }
    *(float4*)(out + base + l0) = o0;
    *(float4*)(out + base + 128 + l0) = o1;
  }
}

// ---------------- qkv 1x1 conv, writes bf16 TRANSPOSED (B, L, 768) ----------
__global__ __launch_bounds__(256)
void qkv1x1(const float* __restrict__ x, const float* __restrict__ w,
            const float* __restrict__ bias, u16* __restrict__ outT)
{
  __shared__ float xs[32][256];
  __shared__ float ws[32][32];   // [ic][oc]
  const int lb = blockIdx.x * 256;
  const int ocb = blockIdx.y * 32;
  const int b = blockIdx.z;
  const int tid = threadIdx.x;
  const int lg = tid & 31, og = tid >> 5;
  const int l0 = lg * 4, oc0 = og * 4;
  float acc[4][8];
#pragma unroll
  for (int i = 0; i < 4; ++i)
#pragma unroll
    for (int j = 0; j < 8; ++j) acc[i][j] = 0.f;

  for (int icc = 0; icc < NC; icc += 32) {
    for (int e = tid; e < 32 * 64; e += 256) {
      const int i = e >> 6, q = (e & 63) * 4;
      *(float4*)&xs[i][q] = *(const float4*)(x + ((size_t)b * NC + icc + i) * NL + lb + q);
    }
    for (int e = tid; e < 1024; e += 256) {
      const int ic = e >> 5, oc = e & 31;
      ws[ic][oc] = w[(size_t)(ocb + oc) * NC + icc + ic];
    }
    __syncthreads();
#pragma unroll 4
    for (int ic = 0; ic < 32; ++ic) {
      const float4 xa = *(const float4*)&xs[ic][l0];
      const float4 xb = *(const float4*)&xs[ic][128 + l0];
      const float4 wv = *(const float4*)&ws[ic][oc0];
      const float* wp = (const float*)&wv;
      const float* xap = (const float*)&xa;
      const float* xbp = (const float*)&xb;
#pragma unroll
      for (int oo = 0; oo < 4; ++oo)
#pragma unroll
        for (int li = 0; li < 4; ++li) {
          acc[oo][li]     = fmaf(wp[oo], xap[li], acc[oo][li]);
          acc[oo][li + 4] = fmaf(wp[oo], xbp[li], acc[oo][li + 4]);
        }
    }
    __syncthreads();
  }
  float bv[4];
#pragma unroll
  for (int oo = 0; oo < 4; ++oo) bv[oo] = bias[ocb + oc0 + oo];
#pragma unroll
  for (int li = 0; li < 8; ++li) {
    const int l = lb + ((li < 4) ? (l0 + li) : (128 + l0 + li - 4));
    ushort4 o;
    o.x = f2bf(acc[0][li] + bv[0]);
    o.y = f2bf(acc[1][li] + bv[1]);
    o.z = f2bf(acc[2][li] + bv[2]);
    o.w = f2bf(acc[3][li] + bv[3]);
    *(ushort4*)(outT + ((size_t)b * NL + l) * 768 + ocb + oc0) = o;
  }
}

// ---------------- flash attention, fp32 math, bf16 qkvT input ----------------
// qkvT layout: (B, L, 768) with channels [0:256)=k, [256:512)=q, [512:768)=v
__global__ __launch_bounds__(256)
void attn(const u16* __restrict__ qkvT, float* __restrict__ av)
{
  __shared__ float ks[32][256];
  __shared__ float vs[32][256];
  const int b = blockIdx.y, qt = blockIdx.x;
  const int tid = threadIdx.x;
  const int qrow = qt * 64 + (tid >> 2);
  const int cc = tid & 3;                 // 64-channel chunk owner
  float qv[64];
  {
    const u16* qp = qkvT + ((size_t)b * NL + qrow) * 768 + 256 + cc * 64;
#pragma unroll
    for (int j = 0; j < 16; ++j) {
      ushort4 u = *(const ushort4*)(qp + j * 4);
      qv[j * 4 + 0] = bf2f(u.x); qv[j * 4 + 1] = bf2f(u.y);
      qv[j * 4 + 2] = bf2f(u.z); qv[j * 4 + 3] = bf2f(u.w);
    }
  }
  float O[64];
#pragma unroll
  for (int j = 0; j < 64; ++j) O[j] = 0.f;
  float m = -1e30f, lsum = 0.f;

  for (int kt = 0; kt < 64; ++kt) {
    __syncthreads();                      // protect LDS from previous tile's readers
    const u16* kb = qkvT + ((size_t)b * NL + kt * 32) * 768;
    for (int e = tid; e < 2048; e += 256) {
      const int r = e >> 6, cq = (e & 63) * 4;
      const u16* p = kb + (size_t)r * 768 + cq;
      ushort4 uk = *(const ushort4*)p;
      ushort4 uv = *(const ushort4*)(p + 512);
      *(float4*)&ks[r][cq] = make_float4(bf2f(uk.x), bf2f(uk.y), bf2f(uk.z), bf2f(uk.w));
      *(float4*)&vs[r][cq] = make_float4(bf2f(uv.x), bf2f(uv.y), bf2f(uv.z), bf2f(uv.w));
    }
    __syncthreads();
    float s[32];
#pragma unroll
    for (int k = 0; k < 32; ++k) {
      float p = 0.f;
      const float* kr = &ks[k][cc * 64];
#pragma unroll
      for (int j = 0; j < 64; j += 4) {
        const float4 kv = *(const float4*)(kr + j);
        p = fmaf(qv[j], kv.x, p);
        p = fmaf(qv[j + 1], kv.y, p);
        p = fmaf(qv[j + 2], kv.z, p);
        p = fmaf(qv[j + 3], kv.w, p);
      }
      p += __shfl_xor(p, 1);
      p += __shfl_xor(p, 2);
      s[k] = p * SCALE;
    }
    float tmax = s[0];
#pragma unroll
    for (int k = 1; k < 32; ++k) tmax = fmaxf(tmax, s[k]);
    const float mn = fmaxf(m, tmax);
    const float corr = __expf(m - mn);
    m = mn;
    float ssum = 0.f;
#pragma unroll
    for (int k = 0; k < 32; ++k) { s[k] = __expf(s[k] - mn); ssum += s[k]; }
    lsum = lsum * corr + ssum;
#pragma unroll
    for (int j = 0; j < 64; ++j) O[j] *= corr;
#pragma unroll
    for (int k = 0; k < 32; ++k) {
      const float pk = s[k];
      const float* vr = &vs[k][cc * 64];
#pragma unroll
      for (int j = 0; j < 64; j += 4) {
        const float4 vv = *(const float4*)(vr + j);
        O[j]     = fmaf(pk, vv.x, O[j]);
        O[j + 1] = fmaf(pk, vv.y, O[j + 1]);
        O[j + 2] = fmaf(pk, vv.z, O[j + 2]);
        O[j + 3] = fmaf(pk, vv.w, O[j + 3]);
      }
    }
  }
  const float inv = 1.f / lsum;
  float* op = av + ((size_t)b * NC + cc * 64) * NL + qrow;
#pragma unroll
  for (int j = 0; j < 64; ++j) op[(size_t)j * NL] = O[j] * inv;
}

extern "C" void kernel_launch(void* const* d_in, const int* in_sizes, int n_in,
                              void* d_out, int out_size, void* d_ws, size_t ws_size,
                              hipStream_t stream)
{
  (void)in_sizes; (void)n_in; (void)out_size; (void)ws_size;
  const float* x        = (const float*)d_in[0];
  const float* t        = (const float*)d_in[1];
  const float* r1_gn1_w = (const float*)d_in[2];
  const float* r1_gn1_b = (const float*)d_in[3];
  const float* r1_c1_w  = (const float*)d_in[4];
  const float* r1_c1_b  = (const float*)d_in[5];
  const float* r1_gn2_w = (const float*)d_in[6];
  const float* r1_gn2_b = (const float*)d_in[7];
  const float* r1_c2_w  = (const float*)d_in[8];
  const float* r1_c2_b  = (const float*)d_in[9];
  const float* r2_gn1_w = (const float*)d_in[10];
  const float* r2_gn1_b = (const float*)d_in[11];
  const float* r2_c1_w  = (const float*)d_in[12];
  const float* r2_c1_b  = (const float*)d_in[13];
  const float* r2_gn2_w = (const float*)d_in[14];
  const float* r2_gn2_b = (const float*)d_in[15];
  const float* r2_c2_w  = (const float*)d_in[16];
  const float* r2_c2_b  = (const float*)d_in[17];
  const float* lin_w    = (const float*)d_in[18];
  const float* lin_b    = (const float*)d_in[19];

  float* out = (float*)d_out;
  // ws layout: buf0 fp32 (33.5MB) | qkvT bf16 (50.3MB, later reused as fp32 scratch)
  float* buf0 = (float*)d_ws;
  u16* qkvT = (u16*)((char*)d_ws + (size_t)NB * NC * NL * 4);
  float* qkvF = (float*)qkvT;

  const dim3 gC(NL / C3_L, NC / 32, NB);   // (8, 8, 16)
  const dim3 gQ(NL / 256, 768 / 32, NB);   // (8, 24, 16)
  const dim3 gA(NL / 64, NB);              // (32, 16)

  // res1: x1 = x + conv2(relu(gn2(conv1(relu(gn1(x))) + t)))
  gn_relu<<<NB * NG, 256, 0, stream>>>(x, r1_gn1_w, r1_gn1_b, buf0);
  conv3<<<gC, 256, 0, stream>>>(buf0, r1_c1_w, r1_c1_b, t, nullptr, out);      // h1 -> out
  gn_relu<<<NB * NG, 256, 0, stream>>>(out, r1_gn2_w, r1_gn2_b, buf0);
  conv3<<<gC, 256, 0, stream>>>(buf0, r1_c2_w, r1_c2_b, nullptr, x, out);      // x1 -> out
  // attention
  qkv1x1<<<gQ, 256, 0, stream>>>(out, lin_w, lin_b, qkvT);
  attn<<<gA, 256, 0, stream>>>(qkvT, buf0);                                    // av -> buf0
  // res2 on av: out = av + conv2(relu(gn2(conv1(relu(gn1(av))) + t)))
  gn_relu<<<NB * NG, 256, 0, stream>>>(buf0, r2_gn1_w, r2_gn1_b, out);
  conv3<<<gC, 256, 0, stream>>>(out, r2_c1_w, r2_c1_b, t, nullptr, qkvF);      // h1' -> qkvF
  gn_relu<<<NB * NG, 256, 0, stream>>>(qkvF, r2_gn2_w, r2_gn2_b, qkvF);        // in-place (safe: per-block self-contained)
  conv3<<<gC, 256, 0, stream>>>(qkvF, r2_c2_w, r2_c2_b, nullptr, buf0, out);   // final -> d_out
}

// Round 2
// 2042.735 us; speedup vs baseline: 2.5838x; 2.5838x over previous
//
#include <hip/hip_runtime.h>

typedef unsigned short u16;
typedef __attribute__((ext_vector_type(8))) short bf16x8;
typedef __attribute__((ext_vector_type(4))) float f32x4;

#define NB 16
#define NC 256
#define NL 2048
#define NG 32
#define CPG 8
#define GN_N (CPG * NL)   // 16384 elements per (batch, group)
#define EPS 1e-5f
#define QSCALE 0.0625f    // 1/sqrt(256), folded into q in qkv1x1 (exact: power of 2)

__device__ __forceinline__ float bf2f(u16 a) {
  union { unsigned u; float f; } v; v.u = (unsigned)a << 16; return v.f;
}
__device__ __forceinline__ u16 f2bf(float f) {
  union { float f; unsigned u; } v; v.f = f;
  return (u16)((v.u + 0x7fffu + ((v.u >> 16) & 1u)) >> 16);
}

// ---------------- GroupNorm + ReLU (in-place safe) ----------------
__global__ __launch_bounds__(256)
void gn_relu(const float* __restrict__ x, const float* __restrict__ gw,
             const float* __restrict__ gb, float* __restrict__ out)
{
  const int b = blockIdx.x / NG, g = blockIdx.x % NG;
  const float4* xp = (const float4*)(x + ((size_t)b * NC + g * CPG) * NL);
  float4* op = (float4*)(out + ((size_t)b * NC + g * CPG) * NL);
  float s = 0.f, ss = 0.f;
  for (int i = threadIdx.x; i < GN_N / 4; i += 256) {
    float4 v = xp[i];
    s += (v.x + v.y) + (v.z + v.w);
    ss += (v.x * v.x + v.y * v.y) + (v.z * v.z + v.w * v.w);
  }
#pragma unroll
  for (int o = 32; o > 0; o >>= 1) { s += __shfl_down(s, o); ss += __shfl_down(ss, o); }
  __shared__ float rs[4], rss[4], stat[2];
  if ((threadIdx.x & 63) == 0) { rs[threadIdx.x >> 6] = s; rss[threadIdx.x >> 6] = ss; }
  __syncthreads();
  if (threadIdx.x == 0) {
    float S = rs[0] + rs[1] + rs[2] + rs[3];
    float SS = rss[0] + rss[1] + rss[2] + rss[3];
    float mean = S * (1.f / GN_N);
    float var = SS * (1.f / GN_N) - mean * mean;
    stat[0] = mean; stat[1] = rsqrtf(var + EPS);
  }
  __syncthreads();
  const float mean = stat[0], inv = stat[1];
  for (int i = threadIdx.x; i < GN_N / 4; i += 256) {
    const int c = g * CPG + (i >> 9);   // (i*4)/2048
    const float ga = gw[c] * inv;
    const float be = gb[c] - mean * ga;
    float4 v = xp[i];
    float4 o;
    o.x = fmaxf(fmaf(v.x, ga, be), 0.f);
    o.y = fmaxf(fmaf(v.y, ga, be), 0.f);
    o.z = fmaxf(fmaf(v.z, ga, be), 0.f);
    o.w = fmaxf(fmaf(v.w, ga, be), 0.f);
    op[i] = o;
  }
}

// ---------------- conv1d k=3 pad=1 (cross-correlation, as lax.conv) ----------
#define C3_L 256
#define C3_IC 32

__global__ __launch_bounds__(256)
void conv3(const float* __restrict__ x, const float* __restrict__ w,
           const float* __restrict__ bias, const float* __restrict__ tadd,
           const float* __restrict__ res, float* __restrict__ out)
{
  __shared__ float xs[C3_IC][260];        // cols 0..257 used (halo +2)
  __shared__ float ws[C3_IC][3][32];      // [ic][d][oc]
  const int lb = blockIdx.x * C3_L;
  const int ocb = blockIdx.y * 32;
  const int b = blockIdx.z;
  const int tid = threadIdx.x;
  const int lg = tid & 31, og = tid >> 5;
  const int l0 = lg * 4, oc0 = og * 4;

  float acc[4][8];
#pragma unroll
  for (int i = 0; i < 4; ++i)
#pragma unroll
    for (int j = 0; j < 8; ++j) acc[i][j] = 0.f;

  for (int icc = 0; icc < NC; icc += C3_IC) {
    for (int e = tid; e < C3_IC * 258; e += 256) {
      const int i = e / 258, j = e % 258;
      const int gl = lb - 1 + j;
      float v = 0.f;
      if ((unsigned)gl < (unsigned)NL)
        v = x[((size_t)b * NC + icc + i) * NL + gl];
      xs[i][j] = v;
    }
    for (int e = tid; e < C3_IC * 3 * 32; e += 256) {
      const int ic = e / 96, d = (e / 32) % 3, oc = e & 31;
      ws[ic][d][oc] = w[((size_t)(ocb + oc) * NC + icc + ic) * 3 + d];
    }
    __syncthreads();
#pragma unroll 2
    for (int ic = 0; ic < C3_IC; ++ic) {
      float xr[12];
      *(float4*)&xr[0] = *(const float4*)&xs[ic][l0];
      *(float2*)&xr[4] = *(const float2*)&xs[ic][l0 + 4];
      *(float4*)&xr[6] = *(const float4*)&xs[ic][128 + l0];
      *(float2*)&xr[10] = *(const float2*)&xs[ic][128 + l0 + 4];
      const float4 wd0 = *(const float4*)&ws[ic][0][oc0];
      const float4 wd1 = *(const float4*)&ws[ic][1][oc0];
      const float4 wd2 = *(const float4*)&ws[ic][2][oc0];
      const float* w0p = (const float*)&wd0;
      const float* w1p = (const float*)&wd1;
      const float* w2p = (const float*)&wd2;
#pragma unroll
      for (int oo = 0; oo < 4; ++oo) {
        const float w0 = w0p[oo], w1 = w1p[oo], w2 = w2p[oo];
#pragma unroll
        for (int li = 0; li < 4; ++li) {
          acc[oo][li]     = fmaf(w2, xr[li + 2], fmaf(w1, xr[li + 1], fmaf(w0, xr[li],     acc[oo][li])));
          acc[oo][li + 4] = fmaf(w2, xr[li + 8], fmaf(w1, xr[li + 7], fmaf(w0, xr[li + 6], acc[oo][li + 4])));
        }
      }
    }
    __syncthreads();
  }
#pragma unroll
  for (int oo = 0; oo < 4; ++oo) {
    const int oc = ocb + oc0 + oo;
    float bv = bias[oc];
    if (tadd) bv += tadd[b * NC + oc];
    const size_t base = ((size_t)b * NC + oc) * NL + lb;
    float4 o0, o1;
    o0.x = acc[oo][0] + bv; o0.y = acc[oo][1] + bv; o0.z = acc[oo][2] + bv; o0.w = acc[oo][3] + bv;
    o1.x = acc[oo][4] + bv; o1.y = acc[oo][5] + bv; o1.z = acc[oo][6] + bv; o1.w = acc[oo][7] + bv;
    if (res) {
      float4 r0 = *(const float4*)(res + base + l0);
      float4 r1 = *(const float4*)(res + base + 128 + l0);
      o0.x += r0.x; o0.y += r0.y; o0.z += r0.z; o0.w += r0.w;
      o1.x += r1.x; o1.y += r1.y; o1.z += r1.z; o1.w += r1.w;
    }
    *(float4*)(out + base + l0) = o0;
    *(float4*)(out + base + 128 + l0) = o1;
  }
}

// ---------------- qkv 1x1 conv ----------------
// k,q -> kq (B, L, 512) bf16 row-major (k cols 0..255, q cols 256..511, q pre-scaled by 1/16)
// v   -> vT (B, C, L) bf16
__global__ __launch_bounds__(256)
void qkv1x1(const float* __restrict__ x, const float* __restrict__ w,
            const float* __restrict__ bias, u16* __restrict__ kq, u16* __restrict__ vT)
{
  __shared__ float xs[32][256];
  __shared__ float ws[32][32];   // [ic][oc]
  const int lb = blockIdx.x * 256;
  const int ocb = blockIdx.y * 32;
  const int b = blockIdx.z;
  const int tid = threadIdx.x;
  const int lg = tid & 31, og = tid >> 5;
  const int l0 = lg * 4, oc0 = og * 4;
  float acc[4][8];
#pragma unroll
  for (int i = 0; i < 4; ++i)
#pragma unroll
    for (int j = 0; j < 8; ++j) acc[i][j] = 0.f;

  for (int icc = 0; icc < NC; icc += 32) {
    for (int e = tid; e < 32 * 64; e += 256) {
      const int i = e >> 6, q = (e & 63) * 4;
      *(float4*)&xs[i][q] = *(const float4*)(x + ((size_t)b * NC + icc + i) * NL + lb + q);
    }
    for (int e = tid; e < 1024; e += 256) {
      const int ic = e >> 5, oc = e & 31;
      ws[ic][oc] = w[(size_t)(ocb + oc) * NC + icc + ic];
    }
    __syncthreads();
#pragma unroll 4
    for (int ic = 0; ic < 32; ++ic) {
      const float4 xa = *(const float4*)&xs[ic][l0];
      const float4 xb = *(const float4*)&xs[ic][128 + l0];
      const float4 wv = *(const float4*)&ws[ic][oc0];
      const float* wp = (const float*)&wv;
      const float* xap = (const float*)&xa;
      const float* xbp = (const float*)&xb;
#pragma unroll
      for (int oo = 0; oo < 4; ++oo)
#pragma unroll
        for (int li = 0; li < 4; ++li) {
          acc[oo][li]     = fmaf(wp[oo], xap[li], acc[oo][li]);
          acc[oo][li + 4] = fmaf(wp[oo], xbp[li], acc[oo][li + 4]);
        }
    }
    __syncthreads();
  }
  float bv[4];
#pragma unroll
  for (int oo = 0; oo < 4; ++oo) bv[oo] = bias[ocb + oc0 + oo];

  if (ocb < 512) {
    const float qs = (ocb >= 256) ? QSCALE : 1.0f;
#pragma unroll
    for (int li = 0; li < 8; ++li) {
      const int l = lb + ((li < 4) ? (l0 + li) : (128 + l0 + li - 4));
      ushort4 o;
      o.x = f2bf((acc[0][li] + bv[0]) * qs);
      o.y = f2bf((acc[1][li] + bv[1]) * qs);
      o.z = f2bf((acc[2][li] + bv[2]) * qs);
      o.w = f2bf((acc[3][li] + bv[3]) * qs);
      *(ushort4*)(kq + ((size_t)b * NL + l) * 512 + ocb + oc0) = o;
    }
  } else {
#pragma unroll
    for (int oo = 0; oo < 4; ++oo) {
      const int ocv = ocb - 512 + oc0 + oo;
      u16* vp = vT + ((size_t)b * NC + ocv) * NL + lb;
      ushort4 s0, s1;
      s0.x = f2bf(acc[oo][0] + bv[oo]); s0.y = f2bf(acc[oo][1] + bv[oo]);
      s0.z = f2bf(acc[oo][2] + bv[oo]); s0.w = f2bf(acc[oo][3] + bv[oo]);
      s1.x = f2bf(acc[oo][4] + bv[oo]); s1.y = f2bf(acc[oo][5] + bv[oo]);
      s1.z = f2bf(acc[oo][6] + bv[oo]); s1.w = f2bf(acc[oo][7] + bv[oo]);
      *(ushort4*)(vp + l0) = s0;
      *(ushort4*)(vp + 128 + l0) = s1;
    }
  }
}

// ---------------- flash attention, bf16 MFMA ----------------
// kq: (B, L, 512) bf16, k=[0:256) q=[256:512) (q pre-scaled); vT: (B, C, L) bf16
// out av: (B, C, L) fp32
#define KVB 64
__global__ __launch_bounds__(256)
void attn_mfma(const u16* __restrict__ kq, const u16* __restrict__ vT,
               float* __restrict__ av)
{
  __shared__ u16 plds[4][16 * 64];     // per-wave P tile, XOR-swizzled
  // XCD-aware remap: each XCD owns 2 batches (K/V working set 6MB -> L2-friendly)
  const int fid = blockIdx.x;
  const int xcd = fid & 7, idx = fid >> 3;
  const int b = (xcd << 1) | (idx & 1);
  const int qt = idx >> 1;

  const int tid = threadIdx.x;
  const int w = tid >> 6, lane = tid & 63;
  const int l15 = lane & 15, lg = lane >> 4;
  const int qb = qt * 64 + w * 16;

  const u16* kqb = kq + (size_t)b * NL * 512;
  const u16* vb = vT + (size_t)b * NC * NL;
  u16* pw = &plds[w][0];

  // Q fragments: A[m=q][k=c], lane: m=l15, k = kk*32 + lg*8 + j
  bf16x8 qf[8];
  {
    const u16* qp = kqb + (size_t)(qb + l15) * 512 + 256 + lg * 8;
#pragma unroll
    for (int kk = 0; kk < 8; ++kk) qf[kk] = *(const bf16x8*)(qp + kk * 32);
  }

  f32x4 o[16];
#pragma unroll
  for (int i = 0; i < 16; ++i) o[i] = (f32x4){0.f, 0.f, 0.f, 0.f};
  float mrow[4], lrow[4];
#pragma unroll
  for (int r = 0; r < 4; ++r) { mrow[r] = -1e30f; lrow[r] = 0.f; }

  const int src = (l15 >> 2) << 4;   // lane holding stats for row l15
  const int rr = l15 & 3;

  for (int kv0 = 0; kv0 < NL; kv0 += KVB) {
    // ---- S = Q * K^T : D[m=q][n=kv] ----
    f32x4 s[4];
    const u16* kbase = kqb + (size_t)(kv0 + l15) * 512 + lg * 8;
#pragma unroll
    for (int n = 0; n < 4; ++n) {
      const u16* kp = kbase + (size_t)n * 16 * 512;
      f32x4 acc = (f32x4){0.f, 0.f, 0.f, 0.f};
#pragma unroll
      for (int kk = 0; kk < 8; ++kk) {
        bf16x8 kf = *(const bf16x8*)(kp + kk * 32);
        acc = __builtin_amdgcn_mfma_f32_16x16x32_bf16(qf[kk], kf, acc, 0, 0, 0);
      }
      s[n] = acc;
    }
    // ---- online softmax (rows m = lg*4 + r, cols = l15 + 16n) ----
    float tm[4];
    bool grow = false;
#pragma unroll
    for (int r = 0; r < 4; ++r) {
      float t = fmaxf(fmaxf(s[0][r], s[1][r]), fmaxf(s[2][r], s[3][r]));
#pragma unroll
      for (int m = 1; m < 16; m <<= 1) t = fmaxf(t, __shfl_xor(t, m));
      tm[r] = t;
      grow = grow || (t > mrow[r]);
    }
    if (__any(grow)) {
      float corr[4];
#pragma unroll
      for (int r = 0; r < 4; ++r) {
        const float mn = fmaxf(mrow[r], tm[r]);
        corr[r] = __expf(mrow[r] - mn);
        mrow[r] = mn;
        lrow[r] *= corr[r];
      }
      const float c0 = __shfl(corr[0], src), c1 = __shfl(corr[1], src);
      const float c2 = __shfl(corr[2], src), c3 = __shfl(corr[3], src);
      const float ccol = rr == 0 ? c0 : rr == 1 ? c1 : rr == 2 ? c2 : c3;
#pragma unroll
      for (int i = 0; i < 16; ++i) {
        o[i][0] *= ccol; o[i][1] *= ccol; o[i][2] *= ccol; o[i][3] *= ccol;
      }
    }
#pragma unroll
    for (int r = 0; r < 4; ++r) {
      float rsum = 0.f;
#pragma unroll
      for (int n = 0; n < 4; ++n) {
        const float e = __expf(s[n][r] - mrow[r]);
        s[n][r] = e;
        rsum += e;
      }
#pragma unroll
      for (int m = 1; m < 16; m <<= 1) rsum += __shfl_xor(rsum, m);
      lrow[r] += rsum;
    }
    // ---- P -> LDS (bf16), swizzled: byte = row*128 + col*2, ^= (row&7)<<4 ----
#pragma unroll
    for (int n = 0; n < 4; ++n)
#pragma unroll
      for (int r = 0; r < 4; ++r) {
        const int row = lg * 4 + r, col = n * 16 + l15;
        int byte = (row << 7) + (col << 1);
        byte ^= (row & 7) << 4;
        *(u16*)((char*)pw + byte) = f2bf(s[n][r]);
      }
    // ---- O^T += V^T * P^T : D[m=c][n=q] ----
#pragma unroll
    for (int ks = 0; ks < 2; ++ks) {
      int rbyte = (l15 << 7) + ks * 64 + (lg << 4);
      rbyte ^= (l15 & 7) << 4;
      const bf16x8 pf = *(const bf16x8*)((const char*)pw + rbyte);
      const u16* vp = vb + (size_t)l15 * NL + kv0 + ks * 32 + lg * 8;
#pragma unroll
      for (int ct = 0; ct < 16; ++ct) {
        const bf16x8 vf = *(const bf16x8*)(vp + (size_t)ct * 16 * NL);
        o[ct] = __builtin_amdgcn_mfma_f32_16x16x32_bf16(vf, pf, o[ct], 0, 0, 0);
      }
    }
  }
  // ---- normalize + store: lane holds c = ct*16 + lg*4 + r, q = qb + l15 ----
  const float v0 = __shfl(lrow[0], src), v1 = __shfl(lrow[1], src);
  const float v2 = __shfl(lrow[2], src), v3 = __shfl(lrow[3], src);
  const float den = rr == 0 ? v0 : rr == 1 ? v1 : rr == 2 ? v2 : v3;
  const float inv = 1.f / den;
  float* op = av + ((size_t)b * NC + lg * 4) * NL + qb + l15;
#pragma unroll
  for (int ct = 0; ct < 16; ++ct)
#pragma unroll
    for (int r = 0; r < 4; ++r)
      op[(size_t)(ct * 16 + r) * NL] = o[ct][r] * inv;
}

extern "C" void kernel_launch(void* const* d_in, const int* in_sizes, int n_in,
                              void* d_out, int out_size, void* d_ws, size_t ws_size,
                              hipStream_t stream)
{
  (void)in_sizes; (void)n_in; (void)out_size; (void)ws_size;
  const float* x        = (const float*)d_in[0];
  const float* t        = (const float*)d_in[1];
  const float* r1_gn1_w = (const float*)d_in[2];
  const float* r1_gn1_b = (const float*)d_in[3];
  const float* r1_c1_w  = (const float*)d_in[4];
  const float* r1_c1_b  = (const float*)d_in[5];
  const float* r1_gn2_w = (const float*)d_in[6];
  const float* r1_gn2_b = (const float*)d_in[7];
  const float* r1_c2_w  = (const float*)d_in[8];
  const float* r1_c2_b  = (const float*)d_in[9];
  const float* r2_gn1_w = (const float*)d_in[10];
  const float* r2_gn1_b = (const float*)d_in[11];
  const float* r2_c1_w  = (const float*)d_in[12];
  const float* r2_c1_b  = (const float*)d_in[13];
  const float* r2_gn2_w = (const float*)d_in[14];
  const float* r2_gn2_b = (const float*)d_in[15];
  const float* r2_c2_w  = (const float*)d_in[16];
  const float* r2_c2_b  = (const float*)d_in[17];
  const float* lin_w    = (const float*)d_in[18];
  const float* lin_b    = (const float*)d_in[19];

  float* out = (float*)d_out;
  // ws layout: buf0 fp32 33.55MB | kq bf16 33.55MB | vT bf16 16.78MB  (= 83.9MB total)
  float* buf0 = (float*)d_ws;
  u16* kq = (u16*)((char*)d_ws + (size_t)NB * NC * NL * 4);
  u16* vT = (u16*)((char*)d_ws + (size_t)NB * NC * NL * 4 + (size_t)NB * NL * 512 * 2);
  float* scr = (float*)kq;   // reused fp32 scratch after attention

  const dim3 gC(NL / C3_L, NC / 32, NB);   // (8, 8, 16)
  const dim3 gQ(NL / 256, 768 / 32, NB);   // (8, 24, 16)

  // res1
  gn_relu<<<NB * NG, 256, 0, stream>>>(x, r1_gn1_w, r1_gn1_b, buf0);
  conv3<<<gC, 256, 0, stream>>>(buf0, r1_c1_w, r1_c1_b, t, nullptr, out);
  gn_relu<<<NB * NG, 256, 0, stream>>>(out, r1_gn2_w, r1_gn2_b, buf0);
  conv3<<<gC, 256, 0, stream>>>(buf0, r1_c2_w, r1_c2_b, nullptr, x, out);
  // attention
  qkv1x1<<<gQ, 256, 0, stream>>>(out, lin_w, lin_b, kq, vT);
  attn_mfma<<<NB * (NL / 64), 256, 0, stream>>>(kq, vT, buf0);   // av -> buf0
  // res2
  gn_relu<<<NB * NG, 256, 0, stream>>>(buf0, r2_gn1_w, r2_gn1_b, out);
  conv3<<<gC, 256, 0, stream>>>(out, r2_c1_w, r2_c1_b, t, nullptr, scr);
  gn_relu<<<NB * NG, 256, 0, stream>>>(scr, r2_gn2_w, r2_gn2_b, scr);
  conv3<<<gC, 256, 0, stream>>>(scr, r2_c2_w, r2_c2_b, nullptr, buf0, out);
}

// Round 3
// 834.031 us; speedup vs baseline: 6.3283x; 2.4492x over previous
//
#include <hip/hip_runtime.h>

typedef unsigned short u16;
typedef __attribute__((ext_vector_type(8))) short bf16x8;
typedef __attribute__((ext_vector_type(4))) float f32x4;

#define NB 16
#define NC 256
#define NL 2048
#define NG 32
#define CPG 8
#define GN_N (CPG * NL)
#define EPS 1e-5f
#define QSCALE 0.0625f    // 1/sqrt(256), folded into packed q-weights/bias
#define TROWS 2050        // 2048 + 2 zero pad rows (l = row-1)

__device__ __forceinline__ float bf2f(u16 a) {
  union { unsigned u; float f; } v; v.u = (unsigned)a << 16; return v.f;
}
__device__ __forceinline__ u16 f2bf(float f) {
  union { float f; unsigned u; } v; v.f = f;
  return (u16)((v.u + 0x7fffu + ((v.u >> 16) & 1u)) >> 16);
}

// ---------------- weight pack: fp32 -> bf16, conv (OC,IC,3)->(3,OC,IC); lin scaled ----
__global__ __launch_bounds__(256)
void pack_w(const float* __restrict__ w1, const float* __restrict__ w2,
            const float* __restrict__ w3, const float* __restrict__ w4,
            const float* __restrict__ lw, const float* __restrict__ lb,
            u16* __restrict__ Wp, u16* __restrict__ Wq, float* __restrict__ bq)
{
  const int a = blockIdx.y;
  const int gid = blockIdx.x * 256 + threadIdx.x;   // < 196608
  if (a < 4) {
    const float* w = a == 0 ? w1 : a == 1 ? w2 : a == 2 ? w3 : w4;
    const int d = gid >> 16, rem = gid & 65535;
    const int oc = rem >> 8, ic = rem & 255;
    Wp[a * 196608 + gid] = f2bf(w[(oc * 256 + ic) * 3 + d]);
  } else {
    const int oc = gid >> 8;
    const float s = (oc >= 256 && oc < 512) ? QSCALE : 1.0f;
    Wq[gid] = f2bf(lw[gid] * s);
    if (gid < 768) bq[gid] = lb[gid] * ((gid >= 256 && gid < 512) ? QSCALE : 1.0f);
  }
}

// ---------------- GroupNorm+ReLU: fp32 (B,C,L) -> bf16 transposed padded (B,2050,256) ----
__global__ __launch_bounds__(256)
void gn_f32_T(const float* __restrict__ x, const float* __restrict__ gw,
              const float* __restrict__ gb, u16* __restrict__ outT)
{
  const int b = blockIdx.x >> 5, g = blockIdx.x & 31;
  const float* xp = x + ((size_t)b * NC + g * CPG) * NL;
  float s = 0.f, ss = 0.f;
  for (int i = threadIdx.x; i < GN_N / 4; i += 256) {
    float4 v = ((const float4*)xp)[i];
    s += (v.x + v.y) + (v.z + v.w);
    ss += (v.x * v.x + v.y * v.y) + (v.z * v.z + v.w * v.w);
  }
#pragma unroll
  for (int o = 32; o > 0; o >>= 1) { s += __shfl_down(s, o); ss += __shfl_down(ss, o); }
  __shared__ float rs[4], rss[4], stat[2];
  if ((threadIdx.x & 63) == 0) { rs[threadIdx.x >> 6] = s; rss[threadIdx.x >> 6] = ss; }
  __syncthreads();
  if (threadIdx.x == 0) {
    float S = rs[0] + rs[1] + rs[2] + rs[3];
    float SS = rss[0] + rss[1] + rss[2] + rss[3];
    float mean = S * (1.f / GN_N);
    float var = SS * (1.f / GN_N) - mean * mean;
    stat[0] = mean; stat[1] = rsqrtf(var + EPS);
  }
  __syncthreads();
  const float mean = stat[0], inv = stat[1];
  float ga[8], be[8];
#pragma unroll
  for (int c = 0; c < 8; ++c) {
    ga[c] = gw[g * 8 + c] * inv;
    be[c] = gb[g * 8 + c] - mean * ga[c];
  }
  __shared__ float xf[8][260];
  for (int lc = 0; lc < NL; lc += 256) {
    __syncthreads();
    for (int e = threadIdx.x; e < 512; e += 256) {
      const int c = e >> 6, j = (e & 63) * 4;
      *(float4*)&xf[c][j] = *(const float4*)&xp[(size_t)c * NL + lc + j];
    }
    __syncthreads();
    const int l = lc + threadIdx.x;
    u16 o[8];
#pragma unroll
    for (int c = 0; c < 8; ++c)
      o[c] = f2bf(fmaxf(fmaf(xf[c][threadIdx.x], ga[c], be[c]), 0.f));
    *(bf16x8*)(outT + ((size_t)b * TROWS + 1 + l) * 256 + g * 8) = *(bf16x8*)o;
  }
  if (threadIdx.x < 2) {
    bf16x8 z = (bf16x8){0,0,0,0,0,0,0,0};
    *(bf16x8*)(outT + ((size_t)b * TROWS + (threadIdx.x ? 2049 : 0)) * 256 + g * 8) = z;
  }
}

// ---------------- GroupNorm+ReLU: bf16 T (B,2050,256) -> bf16 T padded ----
__global__ __launch_bounds__(256)
void gn_T_T(const u16* __restrict__ inT, const float* __restrict__ gw,
            const float* __restrict__ gb, u16* __restrict__ outT)
{
  const int b = blockIdx.x >> 5, g = blockIdx.x & 31;
  const u16* ip = inT + ((size_t)b * TROWS + 1) * 256 + g * 8;
  float s = 0.f, ss = 0.f;
  for (int l = threadIdx.x; l < NL; l += 256) {
    bf16x8 h = *(const bf16x8*)(ip + (size_t)l * 256);
#pragma unroll
    for (int c = 0; c < 8; ++c) {
      const float v = bf2f(((u16*)&h)[c]);
      s += v; ss += v * v;
    }
  }
#pragma unroll
  for (int o = 32; o > 0; o >>= 1) { s += __shfl_down(s, o); ss += __shfl_down(ss, o); }
  __shared__ float rs[4], rss[4], stat[2];
  if ((threadIdx.x & 63) == 0) { rs[threadIdx.x >> 6] = s; rss[threadIdx.x >> 6] = ss; }
  __syncthreads();
  if (threadIdx.x == 0) {
    float S = rs[0] + rs[1] + rs[2] + rs[3];
    float SS = rss[0] + rss[1] + rss[2] + rss[3];
    float mean = S * (1.f / GN_N);
    float var = SS * (1.f / GN_N) - mean * mean;
    stat[0] = mean; stat[1] = rsqrtf(var + EPS);
  }
  __syncthreads();
  const float mean = stat[0], inv = stat[1];
  float ga[8], be[8];
#pragma unroll
  for (int c = 0; c < 8; ++c) {
    ga[c] = gw[g * 8 + c] * inv;
    be[c] = gb[g * 8 + c] - mean * ga[c];
  }
  u16* op = outT + ((size_t)b * TROWS + 1) * 256 + g * 8;
  for (int l = threadIdx.x; l < NL; l += 256) {
    bf16x8 h = *(const bf16x8*)(ip + (size_t)l * 256);
    u16 o[8];
#pragma unroll
    for (int c = 0; c < 8; ++c)
      o[c] = f2bf(fmaxf(fmaf(bf2f(((u16*)&h)[c]), ga[c], be[c]), 0.f));
    *(bf16x8*)(op + (size_t)l * 256) = *(bf16x8*)o;
  }
  if (threadIdx.x < 2) {
    bf16x8 z = (bf16x8){0,0,0,0,0,0,0,0};
    *(bf16x8*)(outT + ((size_t)b * TROWS + (threadIdx.x ? 2049 : 0)) * 256 + g * 8) = z;
  }
}

// ---------------- conv GEMM via MFMA ----------------
// xT: (B,2050,256) bf16 padded; Wp: (KD,OCT,256) bf16; out bf16.
// OCT=256: outT (B,2050,256) data rows. OCT=768: kq (B,2048,512) + vT (B,256,2048).
template<int OCT, int KD, bool HAS_T>
__global__ __launch_bounds__(256)
void conv_mfma(const u16* __restrict__ xT, const u16* __restrict__ Wp,
               const float* __restrict__ bias, const float* __restrict__ tadd,
               u16* __restrict__ outT, u16* __restrict__ vTout)
{
  constexpr int DOFF = (KD == 3) ? 0 : 1;
  __shared__ u16 xs[130 * 128];   // 130 rows x 256B, XOR-swizzled 16B granules
  const int lb = blockIdx.x * 128;
  const int ocb = blockIdx.y * 128;
  const int b = blockIdx.z;
  const int tid = threadIdx.x;
  const int w = tid >> 6, lane = tid & 63;
  const int l15 = lane & 15, lg = lane >> 4;
  const int woc = (w >> 1) * 64, wl = (w & 1) * 64;

  f32x4 acc[4][4];
#pragma unroll
  for (int i = 0; i < 4; ++i)
#pragma unroll
    for (int j = 0; j < 4; ++j) acc[i][j] = (f32x4){0.f, 0.f, 0.f, 0.f};

  const u16* xTb = xT + ((size_t)b * TROWS + lb) * 256;

  for (int ich = 0; ich < 2; ++ich) {
    if (ich) __syncthreads();
    // stage 130 rows x 128 ic (256B/row), swizzle granule: gs = (g&8)|((g^row)&7)
    for (int e = tid; e < 130 * 16; e += 256) {
      const int row = e >> 4, g = e & 15;
      const int gs = (g & 8) | ((g ^ row) & 7);
      const bf16x8 v = *(const bf16x8*)(xTb + (size_t)row * 256 + ich * 128 + g * 8);
      *(bf16x8*)((char*)xs + row * 256 + gs * 16) = v;
    }
    __syncthreads();
    for (int kc = 0; kc < 4; ++kc) {
      bf16x8 af[KD][4];
#pragma unroll
      for (int d = 0; d < KD; ++d)
#pragma unroll
        for (int mf = 0; mf < 4; ++mf)
          af[d][mf] = *(const bf16x8*)(Wp + ((size_t)d * OCT + ocb + woc + mf * 16 + l15) * 256
                                          + ich * 128 + kc * 32 + lg * 8);
      const int gg = kc * 4 + lg;
#pragma unroll
      for (int nf = 0; nf < 4; ++nf) {
#pragma unroll
        for (int d = 0; d < KD; ++d) {
          const int r = wl + nf * 16 + l15 + d + DOFF;
          const int gsr = (gg & 8) | ((gg ^ r) & 7);
          const bf16x8 bf = *(const bf16x8*)((const char*)xs + r * 256 + gsr * 16);
#pragma unroll
          for (int mf = 0; mf < 4; ++mf)
            acc[mf][nf] = __builtin_amdgcn_mfma_f32_16x16x32_bf16(af[d][mf], bf, acc[mf][nf], 0, 0, 0);
        }
      }
    }
  }
  // epilogue
#pragma unroll
  for (int mf = 0; mf < 4; ++mf) {
    const int ocbase = ocb + woc + mf * 16 + lg * 4;
    float4 bv = *(const float4*)&bias[ocbase];
    if (HAS_T) {
      const float4 tv = *(const float4*)&tadd[b * 256 + ocbase];
      bv.x += tv.x; bv.y += tv.y; bv.z += tv.z; bv.w += tv.w;
    }
#pragma unroll
    for (int nf = 0; nf < 4; ++nf) {
      const int l = lb + wl + nf * 16 + l15;
      const f32x4 a = acc[mf][nf];
      const u16 o0 = f2bf(a[0] + bv.x), o1 = f2bf(a[1] + bv.y);
      const u16 o2 = f2bf(a[2] + bv.z), o3 = f2bf(a[3] + bv.w);
      if (OCT == 256) {
        ushort4 st = {o0, o1, o2, o3};
        *(ushort4*)(outT + ((size_t)b * TROWS + 1 + l) * 256 + ocbase) = st;
      } else {
        if (ocb + woc < 512) {
          ushort4 st = {o0, o1, o2, o3};
          *(ushort4*)(outT + ((size_t)b * NL + l) * 512 + ocbase) = st;
        } else {
          const int cv = ocbase - 512;
          vTout[((size_t)b * NC + cv + 0) * NL + l] = o0;
          vTout[((size_t)b * NC + cv + 1) * NL + l] = o1;
          vTout[((size_t)b * NC + cv + 2) * NL + l] = o2;
          vTout[((size_t)b * NC + cv + 3) * NL + l] = o3;
        }
      }
    }
  }
}

// ---------------- x1T = bf16(x (C,L) fp32 + h2T) ----------------
__global__ __launch_bounds__(256)
void addres(const float* __restrict__ x, const u16* __restrict__ h2T,
            u16* __restrict__ x1T)
{
  __shared__ float ta[64][65];
  const int lb = blockIdx.x * 64, cb = blockIdx.y * 64, b = blockIdx.z;
  const int tid = threadIdx.x;
  for (int e = tid; e < 1024; e += 256) {
    const int cr = e >> 4, jj = (e & 15) * 4;
    *(float4*)&ta[cr][jj] = *(const float4*)&x[((size_t)b * NC + cb + cr) * NL + lb + jj];
  }
  __syncthreads();
  const int lr = tid & 63, c0 = (tid >> 6) * 16;
  const size_t rowoff = ((size_t)b * TROWS + 1 + lb + lr) * 256 + cb + c0;
  bf16x8 h0 = *(const bf16x8*)(h2T + rowoff);
  bf16x8 h1 = *(const bf16x8*)(h2T + rowoff + 8);
  u16 o[16];
#pragma unroll
  for (int j = 0; j < 8; ++j) o[j] = f2bf(ta[c0 + j][lr] + bf2f(((u16*)&h0)[j]));
#pragma unroll
  for (int j = 0; j < 8; ++j) o[8 + j] = f2bf(ta[c0 + 8 + j][lr] + bf2f(((u16*)&h1)[j]));
  *(bf16x8*)(x1T + rowoff) = *(bf16x8*)o;
  *(bf16x8*)(x1T + rowoff + 8) = *(bf16x8*)&o[8];
}

// ---------------- out (C,L) fp32 += transpose(h2T) (in-place on av) ----------------
__global__ __launch_bounds__(256)
void final_add(const u16* __restrict__ h2T, float* __restrict__ out)
{
  __shared__ float tb[64][65];
  const int lb = blockIdx.x * 64, cb = blockIdx.y * 64, b = blockIdx.z;
  const int tid = threadIdx.x;
  for (int e = tid; e < 512; e += 256) {
    const int lr = e >> 3, gq = e & 7;
    bf16x8 h = *(const bf16x8*)(h2T + ((size_t)b * TROWS + 1 + lb + lr) * 256 + cb + gq * 8);
#pragma unroll
    for (int j = 0; j < 8; ++j) tb[gq * 8 + j][lr] = bf2f(((u16*)&h)[j]);
  }
  __syncthreads();
  const int cr = tid >> 2, lq = (tid & 3) * 16;
  float* op = out + ((size_t)b * NC + cb + cr) * NL + lb;
#pragma unroll
  for (int jj = 0; jj < 4; ++jj) {
    const int l0 = lq + jj * 4;
    float4 a = *(const float4*)(op + l0);
    a.x += tb[cr][l0]; a.y += tb[cr][l0 + 1]; a.z += tb[cr][l0 + 2]; a.w += tb[cr][l0 + 3];
    *(float4*)(op + l0) = a;
  }
}

// ---------------- flash attention, bf16 MFMA (unchanged from round 2) ----------------
#define KVB 64
__global__ __launch_bounds__(256)
void attn_mfma(const u16* __restrict__ kq, const u16* __restrict__ vT,
               float* __restrict__ av)
{
  __shared__ u16 plds[4][16 * 64];
  const int fid = blockIdx.x;
  const int xcd = fid & 7, idx = fid >> 3;
  const int b = (xcd << 1) | (idx & 1);
  const int qt = idx >> 1;

  const int tid = threadIdx.x;
  const int w = tid >> 6, lane = tid & 63;
  const int l15 = lane & 15, lg = lane >> 4;
  const int qb = qt * 64 + w * 16;

  const u16* kqb = kq + (size_t)b * NL * 512;
  const u16* vb = vT + (size_t)b * NC * NL;
  u16* pw = &plds[w][0];

  bf16x8 qf[8];
  {
    const u16* qp = kqb + (size_t)(qb + l15) * 512 + 256 + lg * 8;
#pragma unroll
    for (int kk = 0; kk < 8; ++kk) qf[kk] = *(const bf16x8*)(qp + kk * 32);
  }

  f32x4 o[16];
#pragma unroll
  for (int i = 0; i < 16; ++i) o[i] = (f32x4){0.f, 0.f, 0.f, 0.f};
  float mrow[4], lrow[4];
#pragma unroll
  for (int r = 0; r < 4; ++r) { mrow[r] = -1e30f; lrow[r] = 0.f; }

  const int src = (l15 >> 2) << 4;
  const int rr = l15 & 3;

  for (int kv0 = 0; kv0 < NL; kv0 += KVB) {
    f32x4 s[4];
    const u16* kbase = kqb + (size_t)(kv0 + l15) * 512 + lg * 8;
#pragma unroll
    for (int n = 0; n < 4; ++n) {
      const u16* kp = kbase + (size_t)n * 16 * 512;
      f32x4 acc = (f32x4){0.f, 0.f, 0.f, 0.f};
#pragma unroll
      for (int kk = 0; kk < 8; ++kk) {
        bf16x8 kf = *(const bf16x8*)(kp + kk * 32);
        acc = __builtin_amdgcn_mfma_f32_16x16x32_bf16(qf[kk], kf, acc, 0, 0, 0);
      }
      s[n] = acc;
    }
    float tm[4];
    bool grow = false;
#pragma unroll
    for (int r = 0; r < 4; ++r) {
      float t = fmaxf(fmaxf(s[0][r], s[1][r]), fmaxf(s[2][r], s[3][r]));
#pragma unroll
      for (int m = 1; m < 16; m <<= 1) t = fmaxf(t, __shfl_xor(t, m));
      tm[r] = t;
      grow = grow || (t > mrow[r]);
    }
    if (__any(grow)) {
      float corr[4];
#pragma unroll
      for (int r = 0; r < 4; ++r) {
        const float mn = fmaxf(mrow[r], tm[r]);
        corr[r] = __expf(mrow[r] - mn);
        mrow[r] = mn;
        lrow[r] *= corr[r];
      }
      const float c0 = __shfl(corr[0], src), c1 = __shfl(corr[1], src);
      const float c2 = __shfl(corr[2], src), c3 = __shfl(corr[3], src);
      const float ccol = rr == 0 ? c0 : rr == 1 ? c1 : rr == 2 ? c2 : c3;
#pragma unroll
      for (int i = 0; i < 16; ++i) {
        o[i][0] *= ccol; o[i][1] *= ccol; o[i][2] *= ccol; o[i][3] *= ccol;
      }
    }
#pragma unroll
    for (int r = 0; r < 4; ++r) {
      float rsum = 0.f;
#pragma unroll
      for (int n = 0; n < 4; ++n) {
        const float e = __expf(s[n][r] - mrow[r]);
        s[n][r] = e;
        rsum += e;
      }
#pragma unroll
      for (int m = 1; m < 16; m <<= 1) rsum += __shfl_xor(rsum, m);
      lrow[r] += rsum;
    }
#pragma unroll
    for (int n = 0; n < 4; ++n)
#pragma unroll
      for (int r = 0; r < 4; ++r) {
        const int row = lg * 4 + r, col = n * 16 + l15;
        int byte = (row << 7) + (col << 1);
        byte ^= (row & 7) << 4;
        *(u16*)((char*)pw + byte) = f2bf(s[n][r]);
      }
#pragma unroll
    for (int ks = 0; ks < 2; ++ks) {
      int rbyte = (l15 << 7) + ks * 64 + (lg << 4);
      rbyte ^= (l15 & 7) << 4;
      const bf16x8 pf = *(const bf16x8*)((const char*)pw + rbyte);
      const u16* vp = vb + (size_t)l15 * NL + kv0 + ks * 32 + lg * 8;
#pragma unroll
      for (int ct = 0; ct < 16; ++ct) {
        const bf16x8 vf = *(const bf16x8*)(vp + (size_t)ct * 16 * NL);
        o[ct] = __builtin_amdgcn_mfma_f32_16x16x32_bf16(vf, pf, o[ct], 0, 0, 0);
      }
    }
  }
  const float v0 = __shfl(lrow[0], src), v1 = __shfl(lrow[1], src);
  const float v2 = __shfl(lrow[2], src), v3 = __shfl(lrow[3], src);
  const float den = rr == 0 ? v0 : rr == 1 ? v1 : rr == 2 ? v2 : v3;
  const float inv = 1.f / den;
  float* op = av + ((size_t)b * NC + lg * 4) * NL + qb + l15;
#pragma unroll
  for (int ct = 0; ct < 16; ++ct)
#pragma unroll
    for (int r = 0; r < 4; ++r)
      op[(size_t)(ct * 16 + r) * NL] = o[ct][r] * inv;
}

extern "C" void kernel_launch(void* const* d_in, const int* in_sizes, int n_in,
                              void* d_out, int out_size, void* d_ws, size_t ws_size,
                              hipStream_t stream)
{
  (void)in_sizes; (void)n_in; (void)out_size; (void)ws_size;
  const float* x        = (const float*)d_in[0];
  const float* t        = (const float*)d_in[1];
  const float* r1_gn1_w = (const float*)d_in[2];
  const float* r1_gn1_b = (const float*)d_in[3];
  const float* r1_c1_w  = (const float*)d_in[4];
  const float* r1_c1_b  = (const float*)d_in[5];
  const float* r1_gn2_w = (const float*)d_in[6];
  const float* r1_gn2_b = (const float*)d_in[7];
  const float* r1_c2_w  = (const float*)d_in[8];
  const float* r1_c2_b  = (const float*)d_in[9];
  const float* r2_gn1_w = (const float*)d_in[10];
  const float* r2_gn1_b = (const float*)d_in[11];
  const float* r2_c1_w  = (const float*)d_in[12];
  const float* r2_c1_b  = (const float*)d_in[13];
  const float* r2_gn2_w = (const float*)d_in[14];
  const float* r2_gn2_b = (const float*)d_in[15];
  const float* r2_c2_w  = (const float*)d_in[16];
  const float* r2_c2_b  = (const float*)d_in[17];
  const float* lin_w    = (const float*)d_in[18];
  const float* lin_b    = (const float*)d_in[19];

  float* out = (float*)d_out;

  // ws layout (bytes):
  const size_t TSZ = (size_t)NB * TROWS * 256 * 2;           // 16,793,600
  u16* tA  = (u16*)d_ws;                                     // bf16 T buffer
  u16* tB  = (u16*)((char*)d_ws + TSZ);                      // bf16 T buffer
  u16* kq  = tB;                                             // (B,2048,512) bf16, spans tB+next
  u16* vT  = (u16*)((char*)d_ws + 3 * TSZ);                  // (B,256,2048) bf16
  u16* Wp  = (u16*)((char*)d_ws + 3 * TSZ + (size_t)NB * NC * NL * 2);
  u16* Wq  = Wp + 4 * 196608;
  float* bq = (float*)(Wq + 196608);

  const dim3 gPack(768, 5);
  const dim3 gC(16, 2, NB);
  const dim3 gQ(16, 6, NB);
  const dim3 gT(32, 4, NB);

  pack_w<<<gPack, 256, 0, stream>>>(r1_c1_w, r1_c2_w, r2_c1_w, r2_c2_w, lin_w, lin_b, Wp, Wq, bq);

  // res1
  gn_f32_T<<<NB * NG, 256, 0, stream>>>(x, r1_gn1_w, r1_gn1_b, tA);
  conv_mfma<256, 3, true><<<gC, 256, 0, stream>>>(tA, Wp, r1_c1_b, t, tB, nullptr);
  gn_T_T<<<NB * NG, 256, 0, stream>>>(tB, r1_gn2_w, r1_gn2_b, tA);
  conv_mfma<256, 3, false><<<gC, 256, 0, stream>>>(tA, Wp + 196608, r1_c2_b, nullptr, tB, nullptr);
  addres<<<gT, 256, 0, stream>>>(x, tB, tA);                 // tA = x1T

  // attention
  conv_mfma<768, 1, false><<<gQ, 256, 0, stream>>>(tA, Wq, bq, nullptr, kq, vT);
  attn_mfma<<<NB * (NL / 64), 256, 0, stream>>>(kq, vT, out);  // av -> d_out (C,L) fp32

  // res2
  gn_f32_T<<<NB * NG, 256, 0, stream>>>(out, r2_gn1_w, r2_gn1_b, tA);
  conv_mfma<256, 3, true><<<gC, 256, 0, stream>>>(tA, Wp + 2 * 196608, r2_c1_b, t, tB, nullptr);
  gn_T_T<<<NB * NG, 256, 0, stream>>>(tB, r2_gn2_w, r2_gn2_b, tA);
  conv_mfma<256, 3, false><<<gC, 256, 0, stream>>>(tA, Wp + 3 * 196608, r2_c2_b, nullptr, tB, nullptr);
  final_add<<<gT, 256, 0, stream>>>(tB, out);                // out = av + h2'
}

// Round 4
// 534.600 us; speedup vs baseline: 9.8728x; 1.5601x over previous
//
#include <hip/hip_runtime.h>

typedef unsigned short u16;
typedef __attribute__((ext_vector_type(8))) short bf16x8;
typedef __attribute__((ext_vector_type(4))) float f32x4;

#define NB 16
#define NC 256
#define NL 2048
#define NG 32
#define CPG 8
#define GN_N (CPG * NL)
#define EPS 1e-5f
#define QSCALE 0.0625f    // 1/sqrt(256), folded into packed q-weights/bias
#define TROWS 2050        // 2048 + 2 zero pad rows (l = row-1)

__device__ __forceinline__ float bf2f(u16 a) {
  union { unsigned u; float f; } v; v.u = (unsigned)a << 16; return v.f;
}
__device__ __forceinline__ u16 f2bf(float f) {
  union { float f; unsigned u; } v; v.f = f;
  return (u16)((v.u + 0x7fffu + ((v.u >> 16) & 1u)) >> 16);
}

// ---------------- weight pack: fp32 -> bf16, conv (OC,IC,3)->(3,OC,IC); lin scaled ----
__global__ __launch_bounds__(256)
void pack_w(const float* __restrict__ w1, const float* __restrict__ w2,
            const float* __restrict__ w3, const float* __restrict__ w4,
            const float* __restrict__ lw, const float* __restrict__ lb,
            u16* __restrict__ Wp, u16* __restrict__ Wq, float* __restrict__ bq)
{
  const int a = blockIdx.y;
  const int gid = blockIdx.x * 256 + threadIdx.x;   // < 196608
  if (a < 4) {
    const float* w = a == 0 ? w1 : a == 1 ? w2 : a == 2 ? w3 : w4;
    const int d = gid >> 16, rem = gid & 65535;
    const int oc = rem >> 8, ic = rem & 255;
    Wp[a * 196608 + gid] = f2bf(w[(oc * 256 + ic) * 3 + d]);
  } else {
    const int oc = gid >> 8;
    const float s = (oc >= 256 && oc < 512) ? QSCALE : 1.0f;
    Wq[gid] = f2bf(lw[gid] * s);
    if (gid < 768) bq[gid] = lb[gid] * ((gid >= 256 && gid < 512) ? QSCALE : 1.0f);
  }
}

// ---------------- GroupNorm+ReLU: fp32 (B,C,L) -> bf16 transposed padded (B,2050,256) ----
__global__ __launch_bounds__(256)
void gn_f32_T(const float* __restrict__ x, const float* __restrict__ gw,
              const float* __restrict__ gb, u16* __restrict__ outT)
{
  const int b = blockIdx.x >> 5, g = blockIdx.x & 31;
  const float* xp = x + ((size_t)b * NC + g * CPG) * NL;
  float s = 0.f, ss = 0.f;
  for (int i = threadIdx.x; i < GN_N / 4; i += 256) {
    float4 v = ((const float4*)xp)[i];
    s += (v.x + v.y) + (v.z + v.w);
    ss += (v.x * v.x + v.y * v.y) + (v.z * v.z + v.w * v.w);
  }
#pragma unroll
  for (int o = 32; o > 0; o >>= 1) { s += __shfl_down(s, o); ss += __shfl_down(ss, o); }
  __shared__ float rs[4], rss[4], stat[2];
  if ((threadIdx.x & 63) == 0) { rs[threadIdx.x >> 6] = s; rss[threadIdx.x >> 6] = ss; }
  __syncthreads();
  if (threadIdx.x == 0) {
    float S = rs[0] + rs[1] + rs[2] + rs[3];
    float SS = rss[0] + rss[1] + rss[2] + rss[3];
    float mean = S * (1.f / GN_N);
    float var = SS * (1.f / GN_N) - mean * mean;
    stat[0] = mean; stat[1] = rsqrtf(var + EPS);
  }
  __syncthreads();
  const float mean = stat[0], inv = stat[1];
  float ga[8], be[8];
#pragma unroll
  for (int c = 0; c < 8; ++c) {
    ga[c] = gw[g * 8 + c] * inv;
    be[c] = gb[g * 8 + c] - mean * ga[c];
  }
  __shared__ float xf[8][260];
  for (int lc = 0; lc < NL; lc += 256) {
    __syncthreads();
    for (int e = threadIdx.x; e < 512; e += 256) {
      const int c = e >> 6, j = (e & 63) * 4;
      *(float4*)&xf[c][j] = *(const float4*)&xp[(size_t)c * NL + lc + j];
    }
    __syncthreads();
    const int l = lc + threadIdx.x;
    u16 o[8];
#pragma unroll
    for (int c = 0; c < 8; ++c)
      o[c] = f2bf(fmaxf(fmaf(xf[c][threadIdx.x], ga[c], be[c]), 0.f));
    *(bf16x8*)(outT + ((size_t)b * TROWS + 1 + l) * 256 + g * 8) = *(bf16x8*)o;
  }
  if (threadIdx.x < 2) {
    bf16x8 z = (bf16x8){0,0,0,0,0,0,0,0};
    *(bf16x8*)(outT + ((size_t)b * TROWS + (threadIdx.x ? 2049 : 0)) * 256 + g * 8) = z;
  }
}

// ---------------- GroupNorm+ReLU: bf16 T (B,2050,256) -> bf16 T padded ----
__global__ __launch_bounds__(256)
void gn_T_T(const u16* __restrict__ inT, const float* __restrict__ gw,
            const float* __restrict__ gb, u16* __restrict__ outT)
{
  const int b = blockIdx.x >> 5, g = blockIdx.x & 31;
  const u16* ip = inT + ((size_t)b * TROWS + 1) * 256 + g * 8;
  float s = 0.f, ss = 0.f;
  for (int l = threadIdx.x; l < NL; l += 256) {
    bf16x8 h = *(const bf16x8*)(ip + (size_t)l * 256);
#pragma unroll
    for (int c = 0; c < 8; ++c) {
      const float v = bf2f(((u16*)&h)[c]);
      s += v; ss += v * v;
    }
  }
#pragma unroll
  for (int o = 32; o > 0; o >>= 1) { s += __shfl_down(s, o); ss += __shfl_down(ss, o); }
  __shared__ float rs[4], rss[4], stat[2];
  if ((threadIdx.x & 63) == 0) { rs[threadIdx.x >> 6] = s; rss[threadIdx.x >> 6] = ss; }
  __syncthreads();
  if (threadIdx.x == 0) {
    float S = rs[0] + rs[1] + rs[2] + rs[3];
    float SS = rss[0] + rss[1] + rss[2] + rss[3];
    float mean = S * (1.f / GN_N);
    float var = SS * (1.f / GN_N) - mean * mean;
    stat[0] = mean; stat[1] = rsqrtf(var + EPS);
  }
  __syncthreads();
  const float mean = stat[0], inv = stat[1];
  float ga[8], be[8];
#pragma unroll
  for (int c = 0; c < 8; ++c) {
    ga[c] = gw[g * 8 + c] * inv;
    be[c] = gb[g * 8 + c] - mean * ga[c];
  }
  u16* op = outT + ((size_t)b * TROWS + 1) * 256 + g * 8;
  for (int l = threadIdx.x; l < NL; l += 256) {
    bf16x8 h = *(const bf16x8*)(ip + (size_t)l * 256);
    u16 o[8];
#pragma unroll
    for (int c = 0; c < 8; ++c)
      o[c] = f2bf(fmaxf(fmaf(bf2f(((u16*)&h)[c]), ga[c], be[c]), 0.f));
    *(bf16x8*)(op + (size_t)l * 256) = *(bf16x8*)o;
  }
  if (threadIdx.x < 2) {
    bf16x8 z = (bf16x8){0,0,0,0,0,0,0,0};
    *(bf16x8*)(outT + ((size_t)b * TROWS + (threadIdx.x ? 2049 : 0)) * 256 + g * 8) = z;
  }
}

// ---------------- conv GEMM via MFMA ----------------
template<int OCT, int KD, bool HAS_T>
__global__ __launch_bounds__(256)
void conv_mfma(const u16* __restrict__ xT, const u16* __restrict__ Wp,
               const float* __restrict__ bias, const float* __restrict__ tadd,
               u16* __restrict__ outT, u16* __restrict__ vTout)
{
  constexpr int DOFF = (KD == 3) ? 0 : 1;
  __shared__ u16 xs[130 * 128];   // 130 rows x 256B, XOR-swizzled 16B granules
  const int lb = blockIdx.x * 128;
  const int ocb = blockIdx.y * 128;
  const int b = blockIdx.z;
  const int tid = threadIdx.x;
  const int w = tid >> 6, lane = tid & 63;
  const int l15 = lane & 15, lg = lane >> 4;
  const int woc = (w >> 1) * 64, wl = (w & 1) * 64;

  f32x4 acc[4][4];
#pragma unroll
  for (int i = 0; i < 4; ++i)
#pragma unroll
    for (int j = 0; j < 4; ++j) acc[i][j] = (f32x4){0.f, 0.f, 0.f, 0.f};

  const u16* xTb = xT + ((size_t)b * TROWS + lb) * 256;

  for (int ich = 0; ich < 2; ++ich) {
    if (ich) __syncthreads();
    for (int e = tid; e < 130 * 16; e += 256) {
      const int row = e >> 4, g = e & 15;
      const int gs = (g & 8) | ((g ^ row) & 7);
      const bf16x8 v = *(const bf16x8*)(xTb + (size_t)row * 256 + ich * 128 + g * 8);
      *(bf16x8*)((char*)xs + row * 256 + gs * 16) = v;
    }
    __syncthreads();
    for (int kc = 0; kc < 4; ++kc) {
      bf16x8 af[KD][4];
#pragma unroll
      for (int d = 0; d < KD; ++d)
#pragma unroll
        for (int mf = 0; mf < 4; ++mf)
          af[d][mf] = *(const bf16x8*)(Wp + ((size_t)d * OCT + ocb + woc + mf * 16 + l15) * 256
                                          + ich * 128 + kc * 32 + lg * 8);
      const int gg = kc * 4 + lg;
#pragma unroll
      for (int nf = 0; nf < 4; ++nf) {
#pragma unroll
        for (int d = 0; d < KD; ++d) {
          const int r = wl + nf * 16 + l15 + d + DOFF;
          const int gsr = (gg & 8) | ((gg ^ r) & 7);
          const bf16x8 bf = *(const bf16x8*)((const char*)xs + r * 256 + gsr * 16);
#pragma unroll
          for (int mf = 0; mf < 4; ++mf)
            acc[mf][nf] = __builtin_amdgcn_mfma_f32_16x16x32_bf16(af[d][mf], bf, acc[mf][nf], 0, 0, 0);
        }
      }
    }
  }
#pragma unroll
  for (int mf = 0; mf < 4; ++mf) {
    const int ocbase = ocb + woc + mf * 16 + lg * 4;
    float4 bv = *(const float4*)&bias[ocbase];
    if (HAS_T) {
      const float4 tv = *(const float4*)&tadd[b * 256 + ocbase];
      bv.x += tv.x; bv.y += tv.y; bv.z += tv.z; bv.w += tv.w;
    }
#pragma unroll
    for (int nf = 0; nf < 4; ++nf) {
      const int l = lb + wl + nf * 16 + l15;
      const f32x4 a = acc[mf][nf];
      const u16 o0 = f2bf(a[0] + bv.x), o1 = f2bf(a[1] + bv.y);
      const u16 o2 = f2bf(a[2] + bv.z), o3 = f2bf(a[3] + bv.w);
      if (OCT == 256) {
        ushort4 st = {o0, o1, o2, o3};
        *(ushort4*)(outT + ((size_t)b * TROWS + 1 + l) * 256 + ocbase) = st;
      } else {
        if (ocb + woc < 512) {
          ushort4 st = {o0, o1, o2, o3};
          *(ushort4*)(outT + ((size_t)b * NL + l) * 512 + ocbase) = st;
        } else {
          const int cv = ocbase - 512;
          vTout[((size_t)b * NC + cv + 0) * NL + l] = o0;
          vTout[((size_t)b * NC + cv + 1) * NL + l] = o1;
          vTout[((size_t)b * NC + cv + 2) * NL + l] = o2;
          vTout[((size_t)b * NC + cv + 3) * NL + l] = o3;
        }
      }
    }
  }
}

// ---------------- x1T = bf16(x (C,L) fp32 + h2T) ----------------
__global__ __launch_bounds__(256)
void addres(const float* __restrict__ x, const u16* __restrict__ h2T,
            u16* __restrict__ x1T)
{
  __shared__ float ta[64][65];
  const int lb = blockIdx.x * 64, cb = blockIdx.y * 64, b = blockIdx.z;
  const int tid = threadIdx.x;
  for (int e = tid; e < 1024; e += 256) {
    const int cr = e >> 4, jj = (e & 15) * 4;
    *(float4*)&ta[cr][jj] = *(const float4*)&x[((size_t)b * NC + cb + cr) * NL + lb + jj];
  }
  __syncthreads();
  const int lr = tid & 63, c0 = (tid >> 6) * 16;
  const size_t rowoff = ((size_t)b * TROWS + 1 + lb + lr) * 256 + cb + c0;
  bf16x8 h0 = *(const bf16x8*)(h2T + rowoff);
  bf16x8 h1 = *(const bf16x8*)(h2T + rowoff + 8);
  u16 o[16];
#pragma unroll
  for (int j = 0; j < 8; ++j) o[j] = f2bf(ta[c0 + j][lr] + bf2f(((u16*)&h0)[j]));
#pragma unroll
  for (int j = 0; j < 8; ++j) o[8 + j] = f2bf(ta[c0 + 8 + j][lr] + bf2f(((u16*)&h1)[j]));
  *(bf16x8*)(x1T + rowoff) = *(bf16x8*)o;
  *(bf16x8*)(x1T + rowoff + 8) = *(bf16x8*)&o[8];
}

// ---------------- out (C,L) fp32 += transpose(h2T) (in-place on av) ----------------
__global__ __launch_bounds__(256)
void final_add(const u16* __restrict__ h2T, float* __restrict__ out)
{
  __shared__ float tb[64][65];
  const int lb = blockIdx.x * 64, cb = blockIdx.y * 64, b = blockIdx.z;
  const int tid = threadIdx.x;
  for (int e = tid; e < 512; e += 256) {
    const int lr = e >> 3, gq = e & 7;
    bf16x8 h = *(const bf16x8*)(h2T + ((size_t)b * TROWS + 1 + lb + lr) * 256 + cb + gq * 8);
#pragma unroll
    for (int j = 0; j < 8; ++j) tb[gq * 8 + j][lr] = bf2f(((u16*)&h)[j]);
  }
  __syncthreads();
  const int cr = tid >> 2, lq = (tid & 3) * 16;
  float* op = out + ((size_t)b * NC + cb + cr) * NL + lb;
#pragma unroll
  for (int jj = 0; jj < 4; ++jj) {
    const int l0 = lq + jj * 4;
    float4 a = *(const float4*)(op + l0);
    a.x += tb[cr][l0]; a.y += tb[cr][l0 + 1]; a.z += tb[cr][l0 + 2]; a.w += tb[cr][l0 + 3];
    *(float4*)(op + l0) = a;
  }
}

// ---------------- flash attention, bf16 MFMA, LDS-staged double-buffered ----------------
// kq: (B, L, 512) bf16, k=[0:256) q=[256:512) (q pre-scaled); vT: (B, C, L) bf16
#define KVB 32
#define NT (NL / KVB)   // 64
#define KSTR 264        // K LDS row stride (u16): 528B -> conflict-free B-frag reads
#define VSTR 40         // V LDS row stride (u16): 80B
#define PSTR 36         // P LDS row stride (u16): 72B

__global__ __launch_bounds__(256, 2)
void attn_mfma(const u16* __restrict__ kq, const u16* __restrict__ vT,
               float* __restrict__ av)
{
  __shared__ u16 ks[2][32 * KSTR];    // 16.5 KB each
  __shared__ u16 vs[2][256 * VSTR];   // 20 KB each
  __shared__ u16 plds[4][16 * PSTR];  // per-wave P

  const int fid = blockIdx.x;
  const int xcd = fid & 7, idx = fid >> 3;
  const int b = (xcd << 1) | (idx & 1);
  const int qt = idx >> 1;

  const int tid = threadIdx.x;
  const int w = tid >> 6, lane = tid & 63;
  const int l15 = lane & 15, lg = lane >> 4;
  const int qb = qt * 64 + w * 16;

  const u16* kqb = kq + (size_t)b * NL * 512;
  const u16* vb  = vT + (size_t)b * NC * NL;
  u16* pw = &plds[w][0];

  // Q fragments: A[m=q][k=c], lane: m=l15, k = kk*32 + lg*8 + j
  bf16x8 qf[8];
  {
    const u16* qp = kqb + (size_t)(qb + l15) * 512 + 256 + lg * 8;
#pragma unroll
    for (int kk = 0; kk < 8; ++kk) qf[kk] = *(const bf16x8*)(qp + kk * 32);
  }

  f32x4 o[16];
#pragma unroll
  for (int i = 0; i < 16; ++i) o[i] = (f32x4){0.f, 0.f, 0.f, 0.f};
  float mrow[4], lrow[4];
#pragma unroll
  for (int r = 0; r < 4; ++r) { mrow[r] = -1e30f; lrow[r] = 0.f; }
  const int src = (l15 >> 2) << 4;
  const int rr = l15 & 3;

  // per-thread staging chunk coords (K: 1024 chunks of 16B; V: 1024 chunks)
  const int kr0 = tid >> 5, kg0 = tid & 31;         // K chunk i: row kr0 + i*8, granule kg0
  const int vc0 = tid >> 2, vg0 = tid & 3;          // V chunk i: c = vc0 + i*64, granule vg0

  bf16x8 kreg[4], vreg[4];
  // ---- prologue: stage tile 0 into buf 0 ----
#pragma unroll
  for (int i = 0; i < 4; ++i) {
    kreg[i] = *(const bf16x8*)(kqb + (size_t)(kr0 + i * 8) * 512 + kg0 * 8);
    vreg[i] = *(const bf16x8*)(vb + (size_t)(vc0 + i * 64) * NL + vg0 * 8);
  }
#pragma unroll
  for (int i = 0; i < 4; ++i) {
    *(bf16x8*)(&ks[0][(kr0 + i * 8) * KSTR + kg0 * 8]) = kreg[i];
    *(bf16x8*)(&vs[0][(vc0 + i * 64) * VSTR + vg0 * 8]) = vreg[i];
  }
  __syncthreads();

  for (int t = 0; t < NT; ++t) {
    const int cur = t & 1;
    const u16* ksc = &ks[cur][0];
    const u16* vsc = &vs[cur][0];
    // ---- issue next tile's global loads (latency hides under compute) ----
    if (t + 1 < NT) {
      const int nkv = (t + 1) * KVB;
#pragma unroll
      for (int i = 0; i < 4; ++i) {
        kreg[i] = *(const bf16x8*)(kqb + (size_t)(nkv + kr0 + i * 8) * 512 + kg0 * 8);
        vreg[i] = *(const bf16x8*)(vb + (size_t)(vc0 + i * 64) * NL + nkv + vg0 * 8);
      }
    }
    // ---- S = Q K^T : D[m=q][n=kv], 2 n-frags x 8 k-frags ----
    f32x4 s[2];
#pragma unroll
    for (int n = 0; n < 2; ++n) {
      f32x4 acc = (f32x4){0.f, 0.f, 0.f, 0.f};
#pragma unroll
      for (int kk = 0; kk < 8; ++kk) {
        const bf16x8 kf = *(const bf16x8*)(ksc + (n * 16 + l15) * KSTR + kk * 32 + lg * 8);
        acc = __builtin_amdgcn_mfma_f32_16x16x32_bf16(qf[kk], kf, acc, 0, 0, 0);
      }
      s[n] = acc;
    }
    // ---- online softmax (rows q = lg*4+r, cols kv = n*16+l15) ----
    float tm[4];
    bool grow = false;
#pragma unroll
    for (int r = 0; r < 4; ++r) {
      float tmax = fmaxf(s[0][r], s[1][r]);
#pragma unroll
      for (int m = 1; m < 16; m <<= 1) tmax = fmaxf(tmax, __shfl_xor(tmax, m));
      tm[r] = tmax;
      grow = grow || (tmax > mrow[r]);
    }
    if (__any(grow)) {
      float corr[4];
#pragma unroll
      for (int r = 0; r < 4; ++r) {
        const float mn = fmaxf(mrow[r], tm[r]);
        corr[r] = __expf(mrow[r] - mn);
        mrow[r] = mn;
        lrow[r] *= corr[r];
      }
      const float c0 = __shfl(corr[0], src), c1 = __shfl(corr[1], src);
      const float c2 = __shfl(corr[2], src), c3 = __shfl(corr[3], src);
      const float ccol = rr == 0 ? c0 : rr == 1 ? c1 : rr == 2 ? c2 : c3;
#pragma unroll
      for (int i = 0; i < 16; ++i) {
        o[i][0] *= ccol; o[i][1] *= ccol; o[i][2] *= ccol; o[i][3] *= ccol;
      }
    }
#pragma unroll
    for (int r = 0; r < 4; ++r) {
      float rsum = 0.f;
#pragma unroll
      for (int n = 0; n < 2; ++n) {
        const float e = __expf(s[n][r] - mrow[r]);
        s[n][r] = e;
        rsum += e;
      }
#pragma unroll
      for (int m = 1; m < 16; m <<= 1) rsum += __shfl_xor(rsum, m);
      lrow[r] += rsum;
    }
    // ---- P -> per-wave LDS (bf16) ----
#pragma unroll
    for (int n = 0; n < 2; ++n)
#pragma unroll
      for (int r = 0; r < 4; ++r)
        pw[(lg * 4 + r) * PSTR + n * 16 + l15] = f2bf(s[n][r]);
    // ---- O^T += V^T P^T : A = V[c][kv], B = P[q][kv] ----
    const bf16x8 pf = *(const bf16x8*)(pw + l15 * PSTR + lg * 8);
#pragma unroll
    for (int ct = 0; ct < 16; ++ct) {
      const bf16x8 vf = *(const bf16x8*)(vsc + (ct * 16 + l15) * VSTR + lg * 8);
      o[ct] = __builtin_amdgcn_mfma_f32_16x16x32_bf16(vf, pf, o[ct], 0, 0, 0);
    }
    // ---- commit staged regs to other buffer, sync ----
    if (t + 1 < NT) {
      const int nxt = cur ^ 1;
#pragma unroll
      for (int i = 0; i < 4; ++i) {
        *(bf16x8*)(&ks[nxt][(kr0 + i * 8) * KSTR + kg0 * 8]) = kreg[i];
        *(bf16x8*)(&vs[nxt][(vc0 + i * 64) * VSTR + vg0 * 8]) = vreg[i];
      }
      __syncthreads();
    }
  }
  // ---- normalize + store: lane holds c = ct*16 + lg*4 + r, q = qb + l15 ----
  const float v0 = __shfl(lrow[0], src), v1 = __shfl(lrow[1], src);
  const float v2 = __shfl(lrow[2], src), v3 = __shfl(lrow[3], src);
  const float den = rr == 0 ? v0 : rr == 1 ? v1 : rr == 2 ? v2 : v3;
  const float inv = 1.f / den;
  float* op = av + ((size_t)b * NC + lg * 4) * NL + qb + l15;
#pragma unroll
  for (int ct = 0; ct < 16; ++ct)
#pragma unroll
    for (int r = 0; r < 4; ++r)
      op[(size_t)(ct * 16 + r) * NL] = o[ct][r] * inv;
}

extern "C" void kernel_launch(void* const* d_in, const int* in_sizes, int n_in,
                              void* d_out, int out_size, void* d_ws, size_t ws_size,
                              hipStream_t stream)
{
  (void)in_sizes; (void)n_in; (void)out_size; (void)ws_size;
  const float* x        = (const float*)d_in[0];
  const float* t        = (const float*)d_in[1];
  const float* r1_gn1_w = (const float*)d_in[2];
  const float* r1_gn1_b = (const float*)d_in[3];
  const float* r1_c1_w  = (const float*)d_in[4];
  const float* r1_c1_b  = (const float*)d_in[5];
  const float* r1_gn2_w = (const float*)d_in[6];
  const float* r1_gn2_b = (const float*)d_in[7];
  const float* r1_c2_w  = (const float*)d_in[8];
  const float* r1_c2_b  = (const float*)d_in[9];
  const float* r2_gn1_w = (const float*)d_in[10];
  const float* r2_gn1_b = (const float*)d_in[11];
  const float* r2_c1_w  = (const float*)d_in[12];
  const float* r2_c1_b  = (const float*)d_in[13];
  const float* r2_gn2_w = (const float*)d_in[14];
  const float* r2_gn2_b = (const float*)d_in[15];
  const float* r2_c2_w  = (const float*)d_in[16];
  const float* r2_c2_b  = (const float*)d_in[17];
  const float* lin_w    = (const float*)d_in[18];
  const float* lin_b    = (const float*)d_in[19];

  float* out = (float*)d_out;

  const size_t TSZ = (size_t)NB * TROWS * 256 * 2;           // 16,793,600
  u16* tA  = (u16*)d_ws;
  u16* tB  = (u16*)((char*)d_ws + TSZ);
  u16* kq  = tB;                                             // (B,2048,512) bf16, spans tB+next
  u16* vT  = (u16*)((char*)d_ws + 3 * TSZ);                  // (B,256,2048) bf16
  u16* Wp  = (u16*)((char*)d_ws + 3 * TSZ + (size_t)NB * NC * NL * 2);
  u16* Wq  = Wp + 4 * 196608;
  float* bq = (float*)(Wq + 196608);

  const dim3 gPack(768, 5);
  const dim3 gC(16, 2, NB);
  const dim3 gQ(16, 6, NB);
  const dim3 gT(32, 4, NB);

  pack_w<<<gPack, 256, 0, stream>>>(r1_c1_w, r1_c2_w, r2_c1_w, r2_c2_w, lin_w, lin_b, Wp, Wq, bq);

  // res1
  gn_f32_T<<<NB * NG, 256, 0, stream>>>(x, r1_gn1_w, r1_gn1_b, tA);
  conv_mfma<256, 3, true><<<gC, 256, 0, stream>>>(tA, Wp, r1_c1_b, t, tB, nullptr);
  gn_T_T<<<NB * NG, 256, 0, stream>>>(tB, r1_gn2_w, r1_gn2_b, tA);
  conv_mfma<256, 3, false><<<gC, 256, 0, stream>>>(tA, Wp + 196608, r1_c2_b, nullptr, tB, nullptr);
  addres<<<gT, 256, 0, stream>>>(x, tB, tA);                 // tA = x1T

  // attention
  conv_mfma<768, 1, false><<<gQ, 256, 0, stream>>>(tA, Wq, bq, nullptr, kq, vT);
  attn_mfma<<<NB * (NL / 64), 256, 0, stream>>>(kq, vT, out);  // av -> d_out (C,L) fp32

  // res2
  gn_f32_T<<<NB * NG, 256, 0, stream>>>(out, r2_gn1_w, r2_gn1_b, tA);
  conv_mfma<256, 3, true><<<gC, 256, 0, stream>>>(tA, Wp + 2 * 196608, r2_c1_b, t, tB, nullptr);
  gn_T_T<<<NB * NG, 256, 0, stream>>>(tB, r2_gn2_w, r2_gn2_b, tA);
  conv_mfma<256, 3, false><<<gC, 256, 0, stream>>>(tA, Wp + 3 * 196608, r2_c2_b, nullptr, tB, nullptr);
  final_add<<<gT, 256, 0, stream>>>(tB, out);                // out = av + h2'
}

// Round 5
// 477.400 us; speedup vs baseline: 11.0558x; 1.1198x over previous
//
#include <hip/hip_runtime.h>

typedef unsigned short u16;
typedef unsigned int u32;
typedef __attribute__((ext_vector_type(8))) short bf16x8;
typedef __attribute__((ext_vector_type(4))) float f32x4;
typedef __attribute__((ext_vector_type(16))) float f32x16;

#define NB 16
#define NC 256
#define NL 2048
#define NG 32
#define CPG 8
#define GN_N (CPG * NL)
#define EPS 1e-5f
#define QSCALE 0.0625f    // 1/sqrt(256), folded into packed q-weights/bias
#define TROWS 2050        // 2048 + 2 zero pad rows (l = row-1)

__device__ __forceinline__ float bf2f(u16 a) {
  union { unsigned u; float f; } v; v.u = (unsigned)a << 16; return v.f;
}
__device__ __forceinline__ u16 f2bf(float f) {
  union { float f; unsigned u; } v; v.f = f;
  return (u16)((v.u + 0x7fffu + ((v.u >> 16) & 1u)) >> 16);
}
__device__ __forceinline__ u32 cvtpk(float lo, float hi) {
  u32 r;
  asm("v_cvt_pk_bf16_f32 %0, %1, %2" : "=v"(r) : "v"(lo), "v"(hi));
  return r;
}

// ---------------- weight pack: fp32 -> bf16, conv (OC,IC,3)->(3,OC,IC); lin scaled ----
__global__ __launch_bounds__(256)
void pack_w(const float* __restrict__ w1, const float* __restrict__ w2,
            const float* __restrict__ w3, const float* __restrict__ w4,
            const float* __restrict__ lw, const float* __restrict__ lb,
            u16* __restrict__ Wp, u16* __restrict__ Wq, float* __restrict__ bq)
{
  const int a = blockIdx.y;
  const int gid = blockIdx.x * 256 + threadIdx.x;   // < 196608
  if (a < 4) {
    const float* w = a == 0 ? w1 : a == 1 ? w2 : a == 2 ? w3 : w4;
    const int d = gid >> 16, rem = gid & 65535;
    const int oc = rem >> 8, ic = rem & 255;
    Wp[a * 196608 + gid] = f2bf(w[(oc * 256 + ic) * 3 + d]);
  } else {
    const int oc = gid >> 8;
    const float s = (oc >= 256 && oc < 512) ? QSCALE : 1.0f;
    Wq[gid] = f2bf(lw[gid] * s);
    if (gid < 768) bq[gid] = lb[gid] * ((gid >= 256 && gid < 512) ? QSCALE : 1.0f);
  }
}

// ---------------- GroupNorm+ReLU: fp32 (B,C,L) -> bf16 transposed padded (B,2050,256) ----
__global__ __launch_bounds__(256)
void gn_f32_T(const float* __restrict__ x, const float* __restrict__ gw,
              const float* __restrict__ gb, u16* __restrict__ outT)
{
  const int b = blockIdx.x >> 5, g = blockIdx.x & 31;
  const float* xp = x + ((size_t)b * NC + g * CPG) * NL;
  float s = 0.f, ss = 0.f;
  for (int i = threadIdx.x; i < GN_N / 4; i += 256) {
    float4 v = ((const float4*)xp)[i];
    s += (v.x + v.y) + (v.z + v.w);
    ss += (v.x * v.x + v.y * v.y) + (v.z * v.z + v.w * v.w);
  }
#pragma unroll
  for (int o = 32; o > 0; o >>= 1) { s += __shfl_down(s, o); ss += __shfl_down(ss, o); }
  __shared__ float rs[4], rss[4], stat[2];
  if ((threadIdx.x & 63) == 0) { rs[threadIdx.x >> 6] = s; rss[threadIdx.x >> 6] = ss; }
  __syncthreads();
  if (threadIdx.x == 0) {
    float S = rs[0] + rs[1] + rs[2] + rs[3];
    float SS = rss[0] + rss[1] + rss[2] + rss[3];
    float mean = S * (1.f / GN_N);
    float var = SS * (1.f / GN_N) - mean * mean;
    stat[0] = mean; stat[1] = rsqrtf(var + EPS);
  }
  __syncthreads();
  const float mean = stat[0], inv = stat[1];
  float ga[8], be[8];
#pragma unroll
  for (int c = 0; c < 8; ++c) {
    ga[c] = gw[g * 8 + c] * inv;
    be[c] = gb[g * 8 + c] - mean * ga[c];
  }
  __shared__ float xf[8][260];
  for (int lc = 0; lc < NL; lc += 256) {
    __syncthreads();
    for (int e = threadIdx.x; e < 512; e += 256) {
      const int c = e >> 6, j = (e & 63) * 4;
      *(float4*)&xf[c][j] = *(const float4*)&xp[(size_t)c * NL + lc + j];
    }
    __syncthreads();
    const int l = lc + threadIdx.x;
    u16 o[8];
#pragma unroll
    for (int c = 0; c < 8; ++c)
      o[c] = f2bf(fmaxf(fmaf(xf[c][threadIdx.x], ga[c], be[c]), 0.f));
    *(bf16x8*)(outT + ((size_t)b * TROWS + 1 + l) * 256 + g * 8) = *(bf16x8*)o;
  }
  if (threadIdx.x < 2) {
    bf16x8 z = (bf16x8){0,0,0,0,0,0,0,0};
    *(bf16x8*)(outT + ((size_t)b * TROWS + (threadIdx.x ? 2049 : 0)) * 256 + g * 8) = z;
  }
}

// ---------------- GroupNorm+ReLU: bf16 T (B,2050,256) -> bf16 T padded ----
__global__ __launch_bounds__(256)
void gn_T_T(const u16* __restrict__ inT, const float* __restrict__ gw,
            const float* __restrict__ gb, u16* __restrict__ outT)
{
  const int b = blockIdx.x >> 5, g = blockIdx.x & 31;
  const u16* ip = inT + ((size_t)b * TROWS + 1) * 256 + g * 8;
  float s = 0.f, ss = 0.f;
  for (int l = threadIdx.x; l < NL; l += 256) {
    bf16x8 h = *(const bf16x8*)(ip + (size_t)l * 256);
#pragma unroll
    for (int c = 0; c < 8; ++c) {
      const float v = bf2f(((u16*)&h)[c]);
      s += v; ss += v * v;
    }
  }
#pragma unroll
  for (int o = 32; o > 0; o >>= 1) { s += __shfl_down(s, o); ss += __shfl_down(ss, o); }
  __shared__ float rs[4], rss[4], stat[2];
  if ((threadIdx.x & 63) == 0) { rs[threadIdx.x >> 6] = s; rss[threadIdx.x >> 6] = ss; }
  __syncthreads();
  if (threadIdx.x == 0) {
    float S = rs[0] + rs[1] + rs[2] + rs[3];
    float SS = rss[0] + rss[1] + rss[2] + rss[3];
    float mean = S * (1.f / GN_N);
    float var = SS * (1.f / GN_N) - mean * mean;
    stat[0] = mean; stat[1] = rsqrtf(var + EPS);
  }
  __syncthreads();
  const float mean = stat[0], inv = stat[1];
  float ga[8], be[8];
#pragma unroll
  for (int c = 0; c < 8; ++c) {
    ga[c] = gw[g * 8 + c] * inv;
    be[c] = gb[g * 8 + c] - mean * ga[c];
  }
  u16* op = outT + ((size_t)b * TROWS + 1) * 256 + g * 8;
  for (int l = threadIdx.x; l < NL; l += 256) {
    bf16x8 h = *(const bf16x8*)(ip + (size_t)l * 256);
    u16 o[8];
#pragma unroll
    for (int c = 0; c < 8; ++c)
      o[c] = f2bf(fmaxf(fmaf(bf2f(((u16*)&h)[c]), ga[c], be[c]), 0.f));
    *(bf16x8*)(op + (size_t)l * 256) = *(bf16x8*)o;
  }
  if (threadIdx.x < 2) {
    bf16x8 z = (bf16x8){0,0,0,0,0,0,0,0};
    *(bf16x8*)(outT + ((size_t)b * TROWS + (threadIdx.x ? 2049 : 0)) * 256 + g * 8) = z;
  }
}

// ---------------- conv GEMM via MFMA ----------------
template<int OCT, int KD, bool HAS_T>
__global__ __launch_bounds__(256)
void conv_mfma(const u16* __restrict__ xT, const u16* __restrict__ Wp,
               const float* __restrict__ bias, const float* __restrict__ tadd,
               u16* __restrict__ outT, u16* __restrict__ vTout)
{
  constexpr int DOFF = (KD == 3) ? 0 : 1;
  __shared__ u16 xs[130 * 128];   // 130 rows x 256B, XOR-swizzled 16B granules
  const int lb = blockIdx.x * 128;
  const int ocb = blockIdx.y * 128;
  const int b = blockIdx.z;
  const int tid = threadIdx.x;
  const int w = tid >> 6, lane = tid & 63;
  const int l15 = lane & 15, lg = lane >> 4;
  const int woc = (w >> 1) * 64, wl = (w & 1) * 64;

  f32x4 acc[4][4];
#pragma unroll
  for (int i = 0; i < 4; ++i)
#pragma unroll
    for (int j = 0; j < 4; ++j) acc[i][j] = (f32x4){0.f, 0.f, 0.f, 0.f};

  const u16* xTb = xT + ((size_t)b * TROWS + lb) * 256;

  for (int ich = 0; ich < 2; ++ich) {
    if (ich) __syncthreads();
    for (int e = tid; e < 130 * 16; e += 256) {
      const int row = e >> 4, g = e & 15;
      const int gs = (g & 8) | ((g ^ row) & 7);
      const bf16x8 v = *(const bf16x8*)(xTb + (size_t)row * 256 + ich * 128 + g * 8);
      *(bf16x8*)((char*)xs + row * 256 + gs * 16) = v;
    }
    __syncthreads();
    for (int kc = 0; kc < 4; ++kc) {
      bf16x8 af[KD][4];
#pragma unroll
      for (int d = 0; d < KD; ++d)
#pragma unroll
        for (int mf = 0; mf < 4; ++mf)
          af[d][mf] = *(const bf16x8*)(Wp + ((size_t)d * OCT + ocb + woc + mf * 16 + l15) * 256
                                          + ich * 128 + kc * 32 + lg * 8);
      const int gg = kc * 4 + lg;
#pragma unroll
      for (int nf = 0; nf < 4; ++nf) {
#pragma unroll
        for (int d = 0; d < KD; ++d) {
          const int r = wl + nf * 16 + l15 + d + DOFF;
          const int gsr = (gg & 8) | ((gg ^ r) & 7);
          const bf16x8 bf = *(const bf16x8*)((const char*)xs + r * 256 + gsr * 16);
#pragma unroll
          for (int mf = 0; mf < 4; ++mf)
            acc[mf][nf] = __builtin_amdgcn_mfma_f32_16x16x32_bf16(af[d][mf], bf, acc[mf][nf], 0, 0, 0);
        }
      }
    }
  }
#pragma unroll
  for (int mf = 0; mf < 4; ++mf) {
    const int ocbase = ocb + woc + mf * 16 + lg * 4;
    float4 bv = *(const float4*)&bias[ocbase];
    if (HAS_T) {
      const float4 tv = *(const float4*)&tadd[b * 256 + ocbase];
      bv.x += tv.x; bv.y += tv.y; bv.z += tv.z; bv.w += tv.w;
    }
#pragma unroll
    for (int nf = 0; nf < 4; ++nf) {
      const int l = lb + wl + nf * 16 + l15;
      const f32x4 a = acc[mf][nf];
      const u16 o0 = f2bf(a[0] + bv.x), o1 = f2bf(a[1] + bv.y);
      const u16 o2 = f2bf(a[2] + bv.z), o3 = f2bf(a[3] + bv.w);
      if (OCT == 256) {
        ushort4 st = {o0, o1, o2, o3};
        *(ushort4*)(outT + ((size_t)b * TROWS + 1 + l) * 256 + ocbase) = st;
      } else {
        if (ocb + woc < 512) {
          ushort4 st = {o0, o1, o2, o3};
          *(ushort4*)(outT + ((size_t)b * NL + l) * 512 + ocbase) = st;
        } else {
          const int cv = ocbase - 512;
          vTout[((size_t)b * NC + cv + 0) * NL + l] = o0;
          vTout[((size_t)b * NC + cv + 1) * NL + l] = o1;
          vTout[((size_t)b * NC + cv + 2) * NL + l] = o2;
          vTout[((size_t)b * NC + cv + 3) * NL + l] = o3;
        }
      }
    }
  }
}

// ---------------- x1T = bf16(x (C,L) fp32 + h2T) ----------------
__global__ __launch_bounds__(256)
void addres(const float* __restrict__ x, const u16* __restrict__ h2T,
            u16* __restrict__ x1T)
{
  __shared__ float ta[64][65];
  const int lb = blockIdx.x * 64, cb = blockIdx.y * 64, b = blockIdx.z;
  const int tid = threadIdx.x;
  for (int e = tid; e < 1024; e += 256) {
    const int cr = e >> 4, jj = (e & 15) * 4;
    *(float4*)&ta[cr][jj] = *(const float4*)&x[((size_t)b * NC + cb + cr) * NL + lb + jj];
  }
  __syncthreads();
  const int lr = tid & 63, c0 = (tid >> 6) * 16;
  const size_t rowoff = ((size_t)b * TROWS + 1 + lb + lr) * 256 + cb + c0;
  bf16x8 h0 = *(const bf16x8*)(h2T + rowoff);
  bf16x8 h1 = *(const bf16x8*)(h2T + rowoff + 8);
  u16 o[16];
#pragma unroll
  for (int j = 0; j < 8; ++j) o[j] = f2bf(ta[c0 + j][lr] + bf2f(((u16*)&h0)[j]));
#pragma unroll
  for (int j = 0; j < 8; ++j) o[8 + j] = f2bf(ta[c0 + 8 + j][lr] + bf2f(((u16*)&h1)[j]));
  *(bf16x8*)(x1T + rowoff) = *(bf16x8*)o;
  *(bf16x8*)(x1T + rowoff + 8) = *(bf16x8*)&o[8];
}

// ---------------- out (C,L) fp32 += transpose(h2T) (in-place on av) ----------------
__global__ __launch_bounds__(256)
void final_add(const u16* __restrict__ h2T, float* __restrict__ out)
{
  __shared__ float tb[64][65];
  const int lb = blockIdx.x * 64, cb = blockIdx.y * 64, b = blockIdx.z;
  const int tid = threadIdx.x;
  for (int e = tid; e < 512; e += 256) {
    const int lr = e >> 3, gq = e & 7;
    bf16x8 h = *(const bf16x8*)(h2T + ((size_t)b * TROWS + 1 + lb + lr) * 256 + cb + gq * 8);
#pragma unroll
    for (int j = 0; j < 8; ++j) tb[gq * 8 + j][lr] = bf2f(((u16*)&h)[j]);
  }
  __syncthreads();
  const int cr = tid >> 2, lq = (tid & 3) * 16;
  float* op = out + ((size_t)b * NC + cb + cr) * NL + lb;
#pragma unroll
  for (int jj = 0; jj < 4; ++jj) {
    const int l0 = lq + jj * 4;
    float4 a = *(const float4*)(op + l0);
    a.x += tb[cr][l0]; a.y += tb[cr][l0 + 1]; a.z += tb[cr][l0 + 2]; a.w += tb[cr][l0 + 3];
    *(float4*)(op + l0) = a;
  }
}

// ---------------- flash attention: 32x32 MFMA, swapped QK^T, in-register softmax ----
// kq: (B, L, 512) bf16, k=[0:256) q=[256:512) (q pre-scaled); vT: (B, C, L) bf16
// Block: 4 waves x 32 q = 128 q rows. Each lane owns ONE q column (q = lane&31).
// S = mfma(K, Q) -> D[m=kv][n=q]; softmax in-lane; P packed via cvt_pk + shfl_xor(32).
#define AKVB 64
#define ANT (NL / AKVB)     // 32 tiles
#define AKSTR 264           // K LDS row stride in u16 (528B): conflict-free 8-lane groups
#define AVSTR 72            // V LDS row stride in u16 (144B)

__global__ __launch_bounds__(256, 1)
void attn_mfma(const u16* __restrict__ kq, const u16* __restrict__ vT,
               float* __restrict__ av)
{
  __shared__ u16 ks[2][64 * AKSTR];    // 33 KB each
  __shared__ u16 vs[2][256 * AVSTR];   // 36 KB each

  const int fid = blockIdx.x;                 // 256 blocks
  const int xcd = fid & 7, idx = fid >> 3;    // idx < 32
  const int b = (xcd << 1) | (idx & 1);       // 2 batches per XCD
  const int qt = idx >> 1;                    // 0..15

  const int tid = threadIdx.x;
  const int w = tid >> 6, lane = tid & 63;
  const int l31 = lane & 31, lh = lane >> 5;
  const int q = qt * 128 + w * 32 + l31;

  const u16* kqb = kq + (size_t)b * NL * 512;
  const u16* vb  = vT + (size_t)b * NC * NL;

  // Q as B-operand: B[k=c][n=q], lane: n=q=l31, k = kk*16 + lh*8 + j
  bf16x8 qf[16];
  {
    const u16* qp = kqb + (size_t)q * 512 + 256 + lh * 8;
#pragma unroll
    for (int kk = 0; kk < 16; ++kk) qf[kk] = *(const bf16x8*)(qp + kk * 16);
  }

  f32x16 o[8];
#pragma unroll
  for (int i = 0; i < 8; ++i)
    o[i] = (f32x16){0.f,0.f,0.f,0.f,0.f,0.f,0.f,0.f,0.f,0.f,0.f,0.f,0.f,0.f,0.f,0.f};
  float m = -1e30f, lsum = 0.f;

  // staging coords: K 64 rows x 512B (32 chunks), V 256 rows x 128B (8 chunks)
  const int krow = tid >> 5, kch = tid & 31;
  const int vrow = tid >> 3, vch = tid & 7;

  bf16x8 kst[8], vst[8];
#pragma unroll
  for (int i = 0; i < 8; ++i) {
    kst[i] = *(const bf16x8*)(kqb + (size_t)(krow + i * 8) * 512 + kch * 8);
    vst[i] = *(const bf16x8*)(vb + (size_t)(vrow + i * 32) * NL + vch * 8);
  }
#pragma unroll
  for (int i = 0; i < 8; ++i) {
    *(bf16x8*)(&ks[0][(krow + i * 8) * AKSTR + kch * 8]) = kst[i];
    *(bf16x8*)(&vs[0][(vrow + i * 32) * AVSTR + vch * 8]) = vst[i];
  }
  __syncthreads();

  for (int t = 0; t < ANT; ++t) {
    const int cur = t & 1;
    // issue next tile's global loads early (T14: latency hides under compute)
    if (t + 1 < ANT) {
      const int nkv = (t + 1) * AKVB;
#pragma unroll
      for (int i = 0; i < 8; ++i) {
        kst[i] = *(const bf16x8*)(kqb + (size_t)(nkv + krow + i * 8) * 512 + kch * 8);
        vst[i] = *(const bf16x8*)(vb + (size_t)(vrow + i * 32) * NL + nkv + vch * 8);
      }
    }
    // ---- S = K*Q (swapped): D[m=kv][n=q], 2 frags (kv 0-31, 32-63) ----
    const u16* kbase = &ks[cur][0];
    f32x16 s0 = (f32x16){0.f,0.f,0.f,0.f,0.f,0.f,0.f,0.f,0.f,0.f,0.f,0.f,0.f,0.f,0.f,0.f};
    f32x16 s1 = (f32x16){0.f,0.f,0.f,0.f,0.f,0.f,0.f,0.f,0.f,0.f,0.f,0.f,0.f,0.f,0.f,0.f};
#pragma unroll
    for (int kk = 0; kk < 16; ++kk) {
      const bf16x8 kf0 = *(const bf16x8*)(kbase + l31 * AKSTR + kk * 16 + lh * 8);
      s0 = __builtin_amdgcn_mfma_f32_32x32x16_bf16(kf0, qf[kk], s0, 0, 0, 0);
      const bf16x8 kf1 = *(const bf16x8*)(kbase + (32 + l31) * AKSTR + kk * 16 + lh * 8);
      s1 = __builtin_amdgcn_mfma_f32_32x32x16_bf16(kf1, qf[kk], s1, 0, 0, 0);
    }
    // ---- in-register online softmax (lane owns q; kv split across lh halves) ----
    float t0 = s0[0], t1 = s1[0];
#pragma unroll
    for (int i = 1; i < 16; ++i) { t0 = fmaxf(t0, s0[i]); t1 = fmaxf(t1, s1[i]); }
    float tm = fmaxf(t0, t1);
    tm = fmaxf(tm, __shfl_xor(tm, 32));
    if (!__all(tm <= m + 8.f)) {          // defer-max (T13): rescale only when needed
      const float mn = fmaxf(m, tm);
      const float corr = __expf(m - mn);
      m = mn; lsum *= corr;
#pragma unroll
      for (int i = 0; i < 8; ++i) o[i] *= corr;
    }
    float sum = 0.f;
#pragma unroll
    for (int i = 0; i < 16; ++i) { s0[i] = __expf(s0[i] - m); sum += s0[i]; }
#pragma unroll
    for (int i = 0; i < 16; ++i) { s1[i] = __expf(s1[i] - m); sum += s1[i]; }
    sum += __shfl_xor(sum, 32);
    lsum += sum;
    // ---- pack P to bf16 B-frags: cvt_pk + cross-half exchange (T12) ----
    u32 pk[16], xp[16];
#pragma unroll
    for (int i = 0; i < 8; ++i) pk[i] = cvtpk(s0[2 * i], s0[2 * i + 1]);
#pragma unroll
    for (int i = 0; i < 8; ++i) pk[8 + i] = cvtpk(s1[2 * i], s1[2 * i + 1]);
#pragma unroll
    for (int i = 0; i < 16; ++i) xp[i] = (u32)__shfl_xor((int)pk[i], 32);
    // ---- O += V*P : A = V[m=c][k=kv] from LDS, B = P[k=kv][n=q] in regs ----
    const u16* vbase = &vs[cur][0];
#pragma unroll
    for (int ksx = 0; ksx < 4; ++ksx) {
      const int base = (ksx >> 1) * 8 + (ksx & 1) * 4;
      union { u32 wd[4]; bf16x8 v; } pu;
      pu.wd[0] = lh ? xp[base + 2] : pk[base + 0];
      pu.wd[1] = lh ? xp[base + 3] : pk[base + 1];
      pu.wd[2] = lh ? pk[base + 2] : xp[base + 0];
      pu.wd[3] = lh ? pk[base + 3] : xp[base + 1];
      const bf16x8 pf = pu.v;
#pragma unroll
      for (int mf = 0; mf < 8; ++mf) {
        const bf16x8 vf = *(const bf16x8*)(vbase + (mf * 32 + l31) * AVSTR + ksx * 16 + lh * 8);
        o[mf] = __builtin_amdgcn_mfma_f32_32x32x16_bf16(vf, pf, o[mf], 0, 0, 0);
      }
    }
    // ---- commit staged regs to the other buffer, one barrier per tile ----
    if (t + 1 < ANT) {
      const int nxt = cur ^ 1;
#pragma unroll
      for (int i = 0; i < 8; ++i) {
        *(bf16x8*)(&ks[nxt][(krow + i * 8) * AKSTR + kch * 8]) = kst[i];
        *(bf16x8*)(&vs[nxt][(vrow + i * 32) * AVSTR + vch * 8]) = vst[i];
      }
      __syncthreads();
    }
  }
  // ---- normalize + store: O[m=c][n=q], c = mf*32 + (r&3)+8*(r>>2)+4*lh, q col ----
  const float inv = 1.f / lsum;
  float* op = av + (size_t)b * NC * NL + q;
#pragma unroll
  for (int mf = 0; mf < 8; ++mf)
#pragma unroll
    for (int r = 0; r < 16; ++r) {
      const int c = mf * 32 + (r & 3) + 8 * (r >> 2) + 4 * lh;
      op[(size_t)c * NL] = o[mf][r] * inv;
    }
}

extern "C" void kernel_launch(void* const* d_in, const int* in_sizes, int n_in,
                              void* d_out, int out_size, void* d_ws, size_t ws_size,
                              hipStream_t stream)
{
  (void)in_sizes; (void)n_in; (void)out_size; (void)ws_size;
  const float* x        = (const float*)d_in[0];
  const float* t        = (const float*)d_in[1];
  const float* r1_gn1_w = (const float*)d_in[2];
  const float* r1_gn1_b = (const float*)d_in[3];
  const float* r1_c1_w  = (const float*)d_in[4];
  const float* r1_c1_b  = (const float*)d_in[5];
  const float* r1_gn2_w = (const float*)d_in[6];
  const float* r1_gn2_b = (const float*)d_in[7];
  const float* r1_c2_w  = (const float*)d_in[8];
  const float* r1_c2_b  = (const float*)d_in[9];
  const float* r2_gn1_w = (const float*)d_in[10];
  const float* r2_gn1_b = (const float*)d_in[11];
  const float* r2_c1_w  = (const float*)d_in[12];
  const float* r2_c1_b  = (const float*)d_in[13];
  const float* r2_gn2_w = (const float*)d_in[14];
  const float* r2_gn2_b = (const float*)d_in[15];
  const float* r2_c2_w  = (const float*)d_in[16];
  const float* r2_c2_b  = (const float*)d_in[17];
  const float* lin_w    = (const float*)d_in[18];
  const float* lin_b    = (const float*)d_in[19];

  float* out = (float*)d_out;

  const size_t TSZ = (size_t)NB * TROWS * 256 * 2;           // 16,793,600
  u16* tA  = (u16*)d_ws;
  u16* tB  = (u16*)((char*)d_ws + TSZ);
  u16* kq  = tB;                                             // (B,2048,512) bf16, spans tB+next
  u16* vT  = (u16*)((char*)d_ws + 3 * TSZ);                  // (B,256,2048) bf16
  u16* Wp  = (u16*)((char*)d_ws + 3 * TSZ + (size_t)NB * NC * NL * 2);
  u16* Wq  = Wp + 4 * 196608;
  float* bq = (float*)(Wq + 196608);

  const dim3 gPack(768, 5);
  const dim3 gC(16, 2, NB);
  const dim3 gQ(16, 6, NB);
  const dim3 gT(32, 4, NB);

  pack_w<<<gPack, 256, 0, stream>>>(r1_c1_w, r1_c2_w, r2_c1_w, r2_c2_w, lin_w, lin_b, Wp, Wq, bq);

  // res1
  gn_f32_T<<<NB * NG, 256, 0, stream>>>(x, r1_gn1_w, r1_gn1_b, tA);
  conv_mfma<256, 3, true><<<gC, 256, 0, stream>>>(tA, Wp, r1_c1_b, t, tB, nullptr);
  gn_T_T<<<NB * NG, 256, 0, stream>>>(tB, r1_gn2_w, r1_gn2_b, tA);
  conv_mfma<256, 3, false><<<gC, 256, 0, stream>>>(tA, Wp + 196608, r1_c2_b, nullptr, tB, nullptr);
  addres<<<gT, 256, 0, stream>>>(x, tB, tA);                 // tA = x1T

  // attention
  conv_mfma<768, 1, false><<<gQ, 256, 0, stream>>>(tA, Wq, bq, nullptr, kq, vT);
  attn_mfma<<<256, 256, 0, stream>>>(kq, vT, out);           // av -> d_out (C,L) fp32

  // res2
  gn_f32_T<<<NB * NG, 256, 0, stream>>>(out, r2_gn1_w, r2_gn1_b, tA);
  conv_mfma<256, 3, true><<<gC, 256, 0, stream>>>(tA, Wp + 2 * 196608, r2_c1_b, t, tB, nullptr);
  gn_T_T<<<NB * NG, 256, 0, stream>>>(tB, r2_gn2_w, r2_gn2_b, tA);
  conv_mfma<256, 3, false><<<gC, 256, 0, stream>>>(tA, Wp + 3 * 196608, r2_c2_b, nullptr, tB, nullptr);
  final_add<<<gT, 256, 0, stream>>>(tB, out);                // out = av + h2'
}

// Round 6
// 445.799 us; speedup vs baseline: 11.8395x; 1.0709x over previous
//
#include <hip/hip_runtime.h>

typedef unsigned short u16;
typedef unsigned int u32;
typedef __attribute__((ext_vector_type(8))) short bf16x8;
typedef __attribute__((ext_vector_type(4))) float f32x4;
typedef __attribute__((ext_vector_type(16))) float f32x16;

#define NB 16
#define NC 256
#define NL 2048
#define NG 32
#define CPG 8
#define GN_N (CPG * NL)
#define EPS 1e-5f
#define QSC2 0.0901684401f   // (1/sqrt(256)) * log2(e): S emerges in log2 domain
#define DEFER 11.54f         // 8 * log2(e)
#define TROWS 2050           // 2048 + 2 zero pad rows (l = row-1)

__device__ __forceinline__ float bf2f(u16 a) {
  union { unsigned u; float f; } v; v.u = (unsigned)a << 16; return v.f;
}
__device__ __forceinline__ u16 f2bf(float f) {
  union { float f; unsigned u; } v; v.f = f;
  return (u16)((v.u + 0x7fffu + ((v.u >> 16) & 1u)) >> 16);
}
__device__ __forceinline__ u32 cvtpk(float lo, float hi) {
  u32 r;
  asm("v_cvt_pk_bf16_f32 %0, %1, %2" : "=v"(r) : "v"(lo), "v"(hi));
  return r;
}
__device__ __forceinline__ float ex2(float x) {
  float r;
  asm("v_exp_f32 %0, %1" : "=v"(r) : "v"(x));   // D = 2^S0
  return r;
}
__device__ __forceinline__ void gld16(const void* gsrc, void* ldst) {
  __builtin_amdgcn_global_load_lds(
      (const __attribute__((address_space(1))) void*)gsrc,
      (__attribute__((address_space(3))) void*)ldst, 16, 0, 0);
}

// ---------------- weight pack: fp32 -> bf16, conv (OC,IC,3)->(3,OC,IC); lin scaled ----
__global__ __launch_bounds__(256)
void pack_w(const float* __restrict__ w1, const float* __restrict__ w2,
            const float* __restrict__ w3, const float* __restrict__ w4,
            const float* __restrict__ lw, const float* __restrict__ lb,
            u16* __restrict__ Wp, u16* __restrict__ Wq, float* __restrict__ bq)
{
  const int a = blockIdx.y;
  const int gid = blockIdx.x * 256 + threadIdx.x;   // < 196608
  if (a < 4) {
    const float* w = a == 0 ? w1 : a == 1 ? w2 : a == 2 ? w3 : w4;
    const int d = gid >> 16, rem = gid & 65535;
    const int oc = rem >> 8, ic = rem & 255;
    Wp[a * 196608 + gid] = f2bf(w[(oc * 256 + ic) * 3 + d]);
  } else {
    const int oc = gid >> 8;
    const float s = (oc >= 256 && oc < 512) ? QSC2 : 1.0f;
    Wq[gid] = f2bf(lw[gid] * s);
    if (gid < 768) bq[gid] = lb[gid] * ((gid >= 256 && gid < 512) ? QSC2 : 1.0f);
  }
}

// ---------------- GroupNorm+ReLU: fp32 (B,C,L) -> bf16 transposed padded (B,2050,256) ----
__global__ __launch_bounds__(256)
void gn_f32_T(const float* __restrict__ x, const float* __restrict__ gw,
              const float* __restrict__ gb, u16* __restrict__ outT)
{
  const int b = blockIdx.x >> 5, g = blockIdx.x & 31;
  const float* xp = x + ((size_t)b * NC + g * CPG) * NL;
  float s = 0.f, ss = 0.f;
  for (int i = threadIdx.x; i < GN_N / 4; i += 256) {
    float4 v = ((const float4*)xp)[i];
    s += (v.x + v.y) + (v.z + v.w);
    ss += (v.x * v.x + v.y * v.y) + (v.z * v.z + v.w * v.w);
  }
#pragma unroll
  for (int o = 32; o > 0; o >>= 1) { s += __shfl_down(s, o); ss += __shfl_down(ss, o); }
  __shared__ float rs[4], rss[4], stat[2];
  if ((threadIdx.x & 63) == 0) { rs[threadIdx.x >> 6] = s; rss[threadIdx.x >> 6] = ss; }
  __syncthreads();
  if (threadIdx.x == 0) {
    float S = rs[0] + rs[1] + rs[2] + rs[3];
    float SS = rss[0] + rss[1] + rss[2] + rss[3];
    float mean = S * (1.f / GN_N);
    float var = SS * (1.f / GN_N) - mean * mean;
    stat[0] = mean; stat[1] = rsqrtf(var + EPS);
  }
  __syncthreads();
  const float mean = stat[0], inv = stat[1];
  float ga[8], be[8];
#pragma unroll
  for (int c = 0; c < 8; ++c) {
    ga[c] = gw[g * 8 + c] * inv;
    be[c] = gb[g * 8 + c] - mean * ga[c];
  }
  __shared__ float xf[8][260];
  for (int lc = 0; lc < NL; lc += 256) {
    __syncthreads();
    for (int e = threadIdx.x; e < 512; e += 256) {
      const int c = e >> 6, j = (e & 63) * 4;
      *(float4*)&xf[c][j] = *(const float4*)&xp[(size_t)c * NL + lc + j];
    }
    __syncthreads();
    const int l = lc + threadIdx.x;
    u16 o[8];
#pragma unroll
    for (int c = 0; c < 8; ++c)
      o[c] = f2bf(fmaxf(fmaf(xf[c][threadIdx.x], ga[c], be[c]), 0.f));
    *(bf16x8*)(outT + ((size_t)b * TROWS + 1 + l) * 256 + g * 8) = *(bf16x8*)o;
  }
  if (threadIdx.x < 2) {
    bf16x8 z = (bf16x8){0,0,0,0,0,0,0,0};
    *(bf16x8*)(outT + ((size_t)b * TROWS + (threadIdx.x ? 2049 : 0)) * 256 + g * 8) = z;
  }
}

// ---------------- GroupNorm+ReLU: bf16 T (B,2050,256) -> bf16 T padded ----
__global__ __launch_bounds__(256)
void gn_T_T(const u16* __restrict__ inT, const float* __restrict__ gw,
            const float* __restrict__ gb, u16* __restrict__ outT)
{
  const int b = blockIdx.x >> 5, g = blockIdx.x & 31;
  const u16* ip = inT + ((size_t)b * TROWS + 1) * 256 + g * 8;
  float s = 0.f, ss = 0.f;
  for (int l = threadIdx.x; l < NL; l += 256) {
    bf16x8 h = *(const bf16x8*)(ip + (size_t)l * 256);
#pragma unroll
    for (int c = 0; c < 8; ++c) {
      const float v = bf2f(((u16*)&h)[c]);
      s += v; ss += v * v;
    }
  }
#pragma unroll
  for (int o = 32; o > 0; o >>= 1) { s += __shfl_down(s, o); ss += __shfl_down(ss, o); }
  __shared__ float rs[4], rss[4], stat[2];
  if ((threadIdx.x & 63) == 0) { rs[threadIdx.x >> 6] = s; rss[threadIdx.x >> 6] = ss; }
  __syncthreads();
  if (threadIdx.x == 0) {
    float S = rs[0] + rs[1] + rs[2] + rs[3];
    float SS = rss[0] + rss[1] + rss[2] + rss[3];
    float mean = S * (1.f / GN_N);
    float var = SS * (1.f / GN_N) - mean * mean;
    stat[0] = mean; stat[1] = rsqrtf(var + EPS);
  }
  __syncthreads();
  const float mean = stat[0], inv = stat[1];
  float ga[8], be[8];
#pragma unroll
  for (int c = 0; c < 8; ++c) {
    ga[c] = gw[g * 8 + c] * inv;
    be[c] = gb[g * 8 + c] - mean * ga[c];
  }
  u16* op = outT + ((size_t)b * TROWS + 1) * 256 + g * 8;
  for (int l = threadIdx.x; l < NL; l += 256) {
    bf16x8 h = *(const bf16x8*)(ip + (size_t)l * 256);
    u16 o[8];
#pragma unroll
    for (int c = 0; c < 8; ++c)
      o[c] = f2bf(fmaxf(fmaf(bf2f(((u16*)&h)[c]), ga[c], be[c]), 0.f));
    *(bf16x8*)(op + (size_t)l * 256) = *(bf16x8*)o;
  }
  if (threadIdx.x < 2) {
    bf16x8 z = (bf16x8){0,0,0,0,0,0,0,0};
    *(bf16x8*)(outT + ((size_t)b * TROWS + (threadIdx.x ? 2049 : 0)) * 256 + g * 8) = z;
  }
}

// ---------------- conv GEMM via MFMA: DMA-staged x (double buf) + W prefetch ----------------
template<int OCT, int KD, bool HAS_T>
__global__ __launch_bounds__(256, 2)
void conv_mfma(const u16* __restrict__ xT, const u16* __restrict__ Wp,
               const float* __restrict__ bias, const float* __restrict__ tadd,
               u16* __restrict__ outT, u16* __restrict__ vTout)
{
  constexpr int DOFF = (KD == 3) ? 0 : 1;
  __shared__ u16 xs[2][130 * 128];   // per-ich 130 rows x 256B, source-XOR-swizzled granules
  const int lb = blockIdx.x * 128;
  const int ocb = blockIdx.y * 128;
  const int b = blockIdx.z;
  const int tid = threadIdx.x;
  const int w = tid >> 6, lane = tid & 63;
  const int l15 = lane & 15, lg = lane >> 4;
  const int woc = (w >> 1) * 64, wl = (w & 1) * 64;

  f32x4 acc[4][4];
#pragma unroll
  for (int i = 0; i < 4; ++i)
#pragma unroll
    for (int j = 0; j < 4; ++j) acc[i][j] = (f32x4){0.f, 0.f, 0.f, 0.f};

  const u16* xTb = xT + ((size_t)b * TROWS + lb) * 256;

  // DMA stage of one ich half: 2080 granules; wave w covers slots [w*512, w*512+512) + tail
  auto stageX = [&](int buf, int ich) {
    u16* xb = &xs[buf][0];
#pragma unroll
    for (int j = 0; j < 8; ++j) {
      const int slot = w * 512 + j * 64 + lane;
      const int row = slot >> 4, g0 = slot & 15;
      const int g = (g0 & 8) | ((g0 ^ row) & 7);
      gld16(xTb + (size_t)row * 256 + ich * 128 + g * 8, xb + (size_t)(w * 512 + j * 64) * 8);
    }
    if (w == 0 && lane < 32) {
      const int slot = 2048 + lane;
      const int row = slot >> 4, g0 = slot & 15;
      const int g = (g0 & 8) | ((g0 ^ row) & 7);
      gld16(xTb + (size_t)row * 256 + ich * 128 + g * 8, xb + (size_t)2048 * 8);
    }
  };
  auto loadW = [&](bf16x8 (&af)[KD][4], int p) {
    const int ich = p >> 2, kc = p & 3;
#pragma unroll
    for (int d = 0; d < KD; ++d)
#pragma unroll
      for (int mf = 0; mf < 4; ++mf)
        af[d][mf] = *(const bf16x8*)(Wp + ((size_t)d * OCT + ocb + woc + mf * 16 + l15) * 256
                                        + ich * 128 + kc * 32 + lg * 8);
  };

  bf16x8 afbuf[2][KD][4];
  stageX(0, 0);
  loadW(afbuf[0], 0);
  __syncthreads();          // drains tile-0 DMA
  stageX(1, 1);             // in flight across phases 0-3

#pragma unroll
  for (int p = 0; p < 8; ++p) {
    if (p == 4) __syncthreads();          // ich1 DMA done (drained per-wave) + all reads of buf0 finished
    if (p < 7) loadW(afbuf[(p + 1) & 1], p + 1);
    const int kc = p & 3;
    const int gg = kc * 4 + lg;
    const char* xb = (const char*)&xs[p >> 2][0];
#pragma unroll
    for (int nf = 0; nf < 4; ++nf) {
#pragma unroll
      for (int d = 0; d < KD; ++d) {
        const int r = wl + nf * 16 + l15 + d + DOFF;
        const int gsr = (gg & 8) | ((gg ^ r) & 7);
        const bf16x8 bf = *(const bf16x8*)(xb + r * 256 + gsr * 16);
#pragma unroll
        for (int mf = 0; mf < 4; ++mf)
          acc[mf][nf] = __builtin_amdgcn_mfma_f32_16x16x32_bf16(afbuf[p & 1][d][mf], bf, acc[mf][nf], 0, 0, 0);
      }
    }
  }
  // epilogue
#pragma unroll
  for (int mf = 0; mf < 4; ++mf) {
    const int ocbase = ocb + woc + mf * 16 + lg * 4;
    float4 bv = *(const float4*)&bias[ocbase];
    if (HAS_T) {
      const float4 tv = *(const float4*)&tadd[b * 256 + ocbase];
      bv.x += tv.x; bv.y += tv.y; bv.z += tv.z; bv.w += tv.w;
    }
#pragma unroll
    for (int nf = 0; nf < 4; ++nf) {
      const int l = lb + wl + nf * 16 + l15;
      const f32x4 a = acc[mf][nf];
      const u16 o0 = f2bf(a[0] + bv.x), o1 = f2bf(a[1] + bv.y);
      const u16 o2 = f2bf(a[2] + bv.z), o3 = f2bf(a[3] + bv.w);
      if (OCT == 256) {
        ushort4 st = {o0, o1, o2, o3};
        *(ushort4*)(outT + ((size_t)b * TROWS + 1 + l) * 256 + ocbase) = st;
      } else {
        if (ocb + woc < 512) {
          ushort4 st = {o0, o1, o2, o3};
          *(ushort4*)(outT + ((size_t)b * NL + l) * 512 + ocbase) = st;
        } else {
          const int cv = ocbase - 512;
          vTout[((size_t)b * NC + cv + 0) * NL + l] = o0;
          vTout[((size_t)b * NC + cv + 1) * NL + l] = o1;
          vTout[((size_t)b * NC + cv + 2) * NL + l] = o2;
          vTout[((size_t)b * NC + cv + 3) * NL + l] = o3;
        }
      }
    }
  }
}

// ---------------- x1T = bf16(x (C,L) fp32 + h2T) ----------------
__global__ __launch_bounds__(256)
void addres(const float* __restrict__ x, const u16* __restrict__ h2T,
            u16* __restrict__ x1T)
{
  __shared__ float ta[64][65];
  const int lb = blockIdx.x * 64, cb = blockIdx.y * 64, b = blockIdx.z;
  const int tid = threadIdx.x;
  for (int e = tid; e < 1024; e += 256) {
    const int cr = e >> 4, jj = (e & 15) * 4;
    *(float4*)&ta[cr][jj] = *(const float4*)&x[((size_t)b * NC + cb + cr) * NL + lb + jj];
  }
  __syncthreads();
  const int lr = tid & 63, c0 = (tid >> 6) * 16;
  const size_t rowoff = ((size_t)b * TROWS + 1 + lb + lr) * 256 + cb + c0;
  bf16x8 h0 = *(const bf16x8*)(h2T + rowoff);
  bf16x8 h1 = *(const bf16x8*)(h2T + rowoff + 8);
  u16 o[16];
#pragma unroll
  for (int j = 0; j < 8; ++j) o[j] = f2bf(ta[c0 + j][lr] + bf2f(((u16*)&h0)[j]));
#pragma unroll
  for (int j = 0; j < 8; ++j) o[8 + j] = f2bf(ta[c0 + 8 + j][lr] + bf2f(((u16*)&h1)[j]));
  *(bf16x8*)(x1T + rowoff) = *(bf16x8*)o;
  *(bf16x8*)(x1T + rowoff + 8) = *(bf16x8*)&o[8];
}

// ---------------- out (C,L) fp32 += transpose(h2T) (in-place on av) ----------------
__global__ __launch_bounds__(256)
void final_add(const u16* __restrict__ h2T, float* __restrict__ out)
{
  __shared__ float tb[64][65];
  const int lb = blockIdx.x * 64, cb = blockIdx.y * 64, b = blockIdx.z;
  const int tid = threadIdx.x;
  for (int e = tid; e < 512; e += 256) {
    const int lr = e >> 3, gq = e & 7;
    bf16x8 h = *(const bf16x8*)(h2T + ((size_t)b * TROWS + 1 + lb + lr) * 256 + cb + gq * 8);
#pragma unroll
    for (int j = 0; j < 8; ++j) tb[gq * 8 + j][lr] = bf2f(((u16*)&h)[j]);
  }
  __syncthreads();
  const int cr = tid >> 2, lq = (tid & 3) * 16;
  float* op = out + ((size_t)b * NC + cb + cr) * NL + lb;
#pragma unroll
  for (int jj = 0; jj < 4; ++jj) {
    const int l0 = lq + jj * 4;
    float4 a = *(const float4*)(op + l0);
    a.x += tb[cr][l0]; a.y += tb[cr][l0 + 1]; a.z += tb[cr][l0 + 2]; a.w += tb[cr][l0 + 3];
    *(float4*)(op + l0) = a;
  }
}

// ---------------- flash attention: 32x32 MFMA, DMA-staged K/V, in-register softmax ----
// kq: (B, L, 512) bf16, k=[0:256) q=[256:512) (q pre-scaled to log2 domain); vT: (B,C,L) bf16
#define AKVB 64
#define ANT (NL / AKVB)     // 32 tiles

__global__ __launch_bounds__(256, 1)
void attn_mfma(const u16* __restrict__ kq, const u16* __restrict__ vT,
               float* __restrict__ av)
{
  __shared__ u16 ks[2][64 * 256];    // 64 kv rows x 512B, granule-XOR swizzled (32 KB each)
  __shared__ u16 vs[2][256 * 64];    // 256 c rows x 128B, granule-XOR swizzled (32 KB each)

  const int fid = blockIdx.x;                 // 256 blocks
  const int xcd = fid & 7, idx = fid >> 3;
  const int b = (xcd << 1) | (idx & 1);       // 2 batches per XCD
  const int qt = idx >> 1;

  const int tid = threadIdx.x;
  const int w = tid >> 6, lane = tid & 63;
  const int l31 = lane & 31, lh = lane >> 5;
  const int q = qt * 128 + w * 32 + l31;

  const u16* kqb = kq + (size_t)b * NL * 512;
  const u16* vb  = vT + (size_t)b * NC * NL;

  // DMA stage: K 2048 granules (64r x 32g), V 2048 granules (256r x 8g); 8+8 instrs/wave
  auto stage = [&](int buf, int kv0) {
#pragma unroll
    for (int j = 0; j < 8; ++j) {
      const int slot = w * 512 + j * 64 + lane;
      const int r = slot >> 5, gs = slot & 31;
      gld16(kqb + (size_t)(kv0 + r) * 512 + ((gs ^ (r & 7)) * 8),
            &ks[buf][(size_t)(w * 512 + j * 64) * 8]);
    }
#pragma unroll
    for (int j = 0; j < 8; ++j) {
      const int slot = w * 512 + j * 64 + lane;
      const int r = slot >> 3, gs = slot & 7;
      gld16(vb + (size_t)r * NL + kv0 + ((gs ^ (r & 7)) * 8),
            &vs[buf][(size_t)(w * 512 + j * 64) * 8]);
    }
  };

  // Q as B-operand: B[k=c][n=q], lane: n=q=l31, k = kk*16 + lh*8 + j
  bf16x8 qf[16];
  {
    const u16* qp = kqb + (size_t)q * 512 + 256 + lh * 8;
#pragma unroll
    for (int kk = 0; kk < 16; ++kk) qf[kk] = *(const bf16x8*)(qp + kk * 16);
  }

  f32x16 o[8];
#pragma unroll
  for (int i = 0; i < 8; ++i)
    o[i] = (f32x16){0.f,0.f,0.f,0.f,0.f,0.f,0.f,0.f,0.f,0.f,0.f,0.f,0.f,0.f,0.f,0.f};
  float m = -1e30f, lsum = 0.f;

  stage(0, 0);
  __syncthreads();

  for (int t = 0; t < ANT; ++t) {
    const int cur = t & 1;
    if (t + 1 < ANT) stage(cur ^ 1, (t + 1) * AKVB);   // explicit early issue (DMA)
    // ---- S = K*Q (swapped): D[m=kv][n=q], rows split by lh ----
    const u16* kbase = &ks[cur][0];
    f32x16 s0 = (f32x16){0.f,0.f,0.f,0.f,0.f,0.f,0.f,0.f,0.f,0.f,0.f,0.f,0.f,0.f,0.f,0.f};
    f32x16 s1 = (f32x16){0.f,0.f,0.f,0.f,0.f,0.f,0.f,0.f,0.f,0.f,0.f,0.f,0.f,0.f,0.f,0.f};
#pragma unroll
    for (int kk = 0; kk < 16; ++kk) {
      const int gn = 2 * kk + lh;
      const bf16x8 kf0 = *(const bf16x8*)(kbase + l31 * 256 + ((gn ^ (l31 & 7)) * 8));
      s0 = __builtin_amdgcn_mfma_f32_32x32x16_bf16(kf0, qf[kk], s0, 0, 0, 0);
      const bf16x8 kf1 = *(const bf16x8*)(kbase + (32 + l31) * 256 + ((gn ^ (l31 & 7)) * 8));
      s1 = __builtin_amdgcn_mfma_f32_32x32x16_bf16(kf1, qf[kk], s1, 0, 0, 0);
    }
    // ---- in-register online softmax in log2 domain ----
    float t0 = s0[0], t1 = s1[0];
#pragma unroll
    for (int i = 1; i < 16; ++i) { t0 = fmaxf(t0, s0[i]); t1 = fmaxf(t1, s1[i]); }
    float tm = fmaxf(t0, t1);
    tm = fmaxf(tm, __shfl_xor(tm, 32));
    if (!__all(tm <= m + DEFER)) {        // defer-max (T13)
      const float mn = fmaxf(m, tm);
      const float corr = ex2(m - mn);
      m = mn; lsum *= corr;
#pragma unroll
      for (int i = 0; i < 8; ++i) o[i] *= corr;
    }
    float sum = 0.f;
#pragma unroll
    for (int i = 0; i < 16; ++i) { s0[i] = ex2(s0[i] - m); sum += s0[i]; }
#pragma unroll
    for (int i = 0; i < 16; ++i) { s1[i] = ex2(s1[i] - m); sum += s1[i]; }
    sum += __shfl_xor(sum, 32);
    lsum += sum;
    // ---- pack P to bf16 B-frags: cvt_pk + 8 cross-half exchanges (T12) ----
    u32 pk[16];
#pragma unroll
    for (int i = 0; i < 8; ++i) pk[i] = cvtpk(s0[2 * i], s0[2 * i + 1]);
#pragma unroll
    for (int i = 0; i < 8; ++i) pk[8 + i] = cvtpk(s1[2 * i], s1[2 * i + 1]);
    // ---- O += V*P : A = V[m=c][k=kv] from LDS, B = P[k=kv][n=q] in regs ----
    const u16* vbase = &vs[cur][0];
#pragma unroll
    for (int ksx = 0; ksx < 4; ++ksx) {
      const int base = (ksx >> 1) * 8 + (ksx & 1) * 4;
      const u32 send0 = lh ? pk[base + 0] : pk[base + 2];
      const u32 send1 = lh ? pk[base + 1] : pk[base + 3];
      const u32 r0 = (u32)__shfl_xor((int)send0, 32);
      const u32 r1 = (u32)__shfl_xor((int)send1, 32);
      union { u32 wd[4]; bf16x8 v; } pu;
      pu.wd[0] = lh ? r0 : pk[base + 0];
      pu.wd[1] = lh ? r1 : pk[base + 1];
      pu.wd[2] = lh ? pk[base + 2] : r0;
      pu.wd[3] = lh ? pk[base + 3] : r1;
      const bf16x8 pf = pu.v;
      const int gn = 2 * ksx + lh;
#pragma unroll
      for (int mf = 0; mf < 8; ++mf) {
        const int row = mf * 32 + l31;
        const bf16x8 vf = *(const bf16x8*)(vbase + row * 64 + ((gn ^ (row & 7)) * 8));
        o[mf] = __builtin_amdgcn_mfma_f32_32x32x16_bf16(vf, pf, o[mf], 0, 0, 0);
      }
    }
    if (t + 1 < ANT) __syncthreads();     // drains this tile's DMA (issued ~full tile ago)
  }
  // ---- normalize + store: O[m=c][n=q], c = mf*32 + (r&3)+8*(r>>2)+4*lh ----
  const float inv = 1.f / lsum;
  float* op = av + (size_t)b * NC * NL + q;
#pragma unroll
  for (int mf = 0; mf < 8; ++mf)
#pragma unroll
    for (int r = 0; r < 16; ++r) {
      const int c = mf * 32 + (r & 3) + 8 * (r >> 2) + 4 * lh;
      op[(size_t)c * NL] = o[mf][r] * inv;
    }
}

extern "C" void kernel_launch(void* const* d_in, const int* in_sizes, int n_in,
                              void* d_out, int out_size, void* d_ws, size_t ws_size,
                              hipStream_t stream)
{
  (void)in_sizes; (void)n_in; (void)out_size; (void)ws_size;
  const float* x        = (const float*)d_in[0];
  const float* t        = (const float*)d_in[1];
  const float* r1_gn1_w = (const float*)d_in[2];
  const float* r1_gn1_b = (const float*)d_in[3];
  const float* r1_c1_w  = (const float*)d_in[4];
  const float* r1_c1_b  = (const float*)d_in[5];
  const float* r1_gn2_w = (const float*)d_in[6];
  const float* r1_gn2_b = (const float*)d_in[7];
  const float* r1_c2_w  = (const float*)d_in[8];
  const float* r1_c2_b  = (const float*)d_in[9];
  const float* r2_gn1_w = (const float*)d_in[10];
  const float* r2_gn1_b = (const float*)d_in[11];
  const float* r2_c1_w  = (const float*)d_in[12];
  const float* r2_c1_b  = (const float*)d_in[13];
  const float* r2_gn2_w = (const float*)d_in[14];
  const float* r2_gn2_b = (const float*)d_in[15];
  const float* r2_c2_w  = (const float*)d_in[16];
  const float* r2_c2_b  = (const float*)d_in[17];
  const float* lin_w    = (const float*)d_in[18];
  const float* lin_b    = (const float*)d_in[19];

  float* out = (float*)d_out;

  const size_t TSZ = (size_t)NB * TROWS * 256 * 2;           // 16,793,600
  u16* tA  = (u16*)d_ws;
  u16* tB  = (u16*)((char*)d_ws + TSZ);
  u16* kq  = tB;                                             // (B,2048,512) bf16, spans tB+next
  u16* vT  = (u16*)((char*)d_ws + 3 * TSZ);                  // (B,256,2048) bf16
  u16* Wp  = (u16*)((char*)d_ws + 3 * TSZ + (size_t)NB * NC * NL * 2);
  u16* Wq  = Wp + 4 * 196608;
  float* bq = (float*)(Wq + 196608);

  const dim3 gPack(768, 5);
  const dim3 gC(16, 2, NB);
  const dim3 gQ(16, 6, NB);
  const dim3 gT(32, 4, NB);

  pack_w<<<gPack, 256, 0, stream>>>(r1_c1_w, r1_c2_w, r2_c1_w, r2_c2_w, lin_w, lin_b, Wp, Wq, bq);

  // res1
  gn_f32_T<<<NB * NG, 256, 0, stream>>>(x, r1_gn1_w, r1_gn1_b, tA);
  conv_mfma<256, 3, true><<<gC, 256, 0, stream>>>(tA, Wp, r1_c1_b, t, tB, nullptr);
  gn_T_T<<<NB * NG, 256, 0, stream>>>(tB, r1_gn2_w, r1_gn2_b, tA);
  conv_mfma<256, 3, false><<<gC, 256, 0, stream>>>(tA, Wp + 196608, r1_c2_b, nullptr, tB, nullptr);
  addres<<<gT, 256, 0, stream>>>(x, tB, tA);                 // tA = x1T

  // attention
  conv_mfma<768, 1, false><<<gQ, 256, 0, stream>>>(tA, Wq, bq, nullptr, kq, vT);
  attn_mfma<<<256, 256, 0, stream>>>(kq, vT, out);           // av -> d_out (C,L) fp32

  // res2
  gn_f32_T<<<NB * NG, 256, 0, stream>>>(out, r2_gn1_w, r2_gn1_b, tA);
  conv_mfma<256, 3, true><<<gC, 256, 0, stream>>>(tA, Wp + 2 * 196608, r2_c1_b, t, tB, nullptr);
  gn_T_T<<<NB * NG, 256, 0, stream>>>(tB, r2_gn2_w, r2_gn2_b, tA);
  conv_mfma<256, 3, false><<<gC, 256, 0, stream>>>(tA, Wp + 3 * 196608, r2_c2_b, nullptr, tB, nullptr);
  final_add<<<gT, 256, 0, stream>>>(tB, out);                // out = av + h2'
}